// Round 9
// baseline (367.079 us; speedup 1.0000x reference)
//
#include <hip/hip_runtime.h>

typedef unsigned short u16;
typedef unsigned int u32;
typedef short bf16x8 __attribute__((ext_vector_type(8)));
typedef float f32x4 __attribute__((ext_vector_type(4)));
typedef unsigned int u32x2 __attribute__((ext_vector_type(2)));
typedef unsigned int u32x4 __attribute__((ext_vector_type(4)));

#define D_MODEL 1024
#define NH 16
#define DK 64
#define DFF 4096
#define BATCH 2
#define SEQ 2048
#define BL (BATCH*SEQ)
#define NQKV 3072
// fold (1/sqrt(64)) * log2(e) into Q so softmax is raw exp2 (v_exp_f32)
#define Q_SCALE 0.18033688011f

__device__ __forceinline__ float bfraw2f(u16 u) {
    union { u32 i; float f; } c; c.i = ((u32)u) << 16; return c.f;
}
__device__ __forceinline__ u16 f2bfraw(float f) {
    union { float f; u32 i; } c; c.f = f;
    u32 i = c.i;
    u32 lsb = (i >> 16) & 1u;
    i += 0x7fffu + lsb;
    return (u16)(i >> 16);
}
__device__ __forceinline__ u32 fasu(float f) {
    union { float f; u32 i; } c; c.f = f; return c.i;
}
// pack two f32 -> (bf16(hi)<<16)|bf16(lo), round-to-nearest via +0x8000
__device__ __forceinline__ u32 pack_bf2(float lo, float hi) {
    return __builtin_amdgcn_perm(fasu(hi) + 0x8000u, fasu(lo) + 0x8000u,
                                 0x07060302u);
}
// async global->LDS 16B per lane (dest = wave-uniform base + lane*16)
__device__ __forceinline__ void gload_lds16(const u16* g, u16* l) {
    __builtin_amdgcn_global_load_lds(
        (const __attribute__((address_space(1))) void*)g,
        (__attribute__((address_space(3))) void*)l, 16, 0, 0);
}

// ---------------- merged prep: weight transposes + bias concat + x cast -----
// grid (1024, 1, 7), 256 thr.
// z=0..2: Wq/Wk/Wv per-head transpose into fused [3072][1024] B^T layout
//         (z=0 blocks 256..267 also do the bias concat).
// z=3: Wo (1024x1024). z=4: W1 (1024x4096). z=5: W2 (4096x1024).
// z=6: x f32 -> bf16 cast, 4 chunks per block (grid-stride).
__global__ __launch_bounds__(256) void prep_weights(
    const float* __restrict__ Wq, const float* __restrict__ Wk,
    const float* __restrict__ Wv, const float* __restrict__ Wo,
    const float* __restrict__ W1, const float* __restrict__ W2,
    const float* __restrict__ bq, const float* __restrict__ bk,
    const float* __restrict__ bv, const float* __restrict__ x,
    u16* __restrict__ wqkv_t, u16* __restrict__ wo_t,
    u16* __restrict__ w1_t, u16* __restrict__ w2_t,
    float* __restrict__ bqkv, u16* __restrict__ x_bf) {
    __shared__ u16 t[64][65];
    const int z = blockIdx.z, bx = blockIdx.x;
    const int col = threadIdx.x & 63, rr = threadIdx.x >> 6;

    if (z == 6) {
        // cast x: 4096*1024 f32 -> bf16; 1024 blocks x 4 chunks x 1024 elems
#pragma unroll
        for (int j = 0; j < 4; j++) {
            int i = (((j << 10) + bx) * 256 + threadIdx.x) * 4;
            f32x4 v = *(const f32x4*)&x[i];
#pragma unroll
            for (int e = 0; e < 4; e++) x_bf[i + e] = f2bfraw(v[e]);
        }
        return;
    }

    if (z < 3) {
        if (bx >= 256) {
            if (z == 0 && bx < 268) {
                int i = (bx - 256) * 256 + threadIdx.x;
                bqkv[i] = (i < 1024) ? bq[i]
                        : (i < 2048) ? bk[i - 1024] : bv[i - 2048];
            }
            return;
        }
        const int d0 = (bx & 15) * 64, h = bx >> 4;
        const float* W = (z == 0) ? Wq : (z == 1) ? Wk : Wv;
        const float* src = W + (size_t)h * D_MODEL * DK;
        for (int i = rr; i < 64; i += 4)
            t[i][col] = f2bfraw(src[(size_t)(d0 + i) * DK + col]);
        __syncthreads();
        u16* dst = wqkv_t + (size_t)(z * 1024 + h * 64) * D_MODEL;
        for (int i = rr; i < 64; i += 4)
            dst[(size_t)i * D_MODEL + d0 + col] = t[col][i];
        return;
    }

    const float* in; u16* out; int R, C;
    if (z == 3)      { in = Wo; out = wo_t; R = 1024; C = 1024; }
    else if (z == 4) { in = W1; out = w1_t; R = 1024; C = 4096; }
    else             { in = W2; out = w2_t; R = 4096; C = 1024; }
    const int ctiles = C >> 6;
    const int rt = bx / ctiles, ct = bx % ctiles;
    if (rt >= (R >> 6)) return;
    const int c0 = ct * 64, r0 = rt * 64;
    for (int i = rr; i < 64; i += 4)
        t[i][col] = f2bfraw(in[(size_t)(r0 + i) * C + c0 + col]);
    __syncthreads();
    for (int i = rr; i < 64; i += 4)
        out[(size_t)(c0 + i) * R + r0 + col] = t[col][i];
}

// ---------------- GEMM: C[M][N] = A[M][K] @ Bt[N][K]^T ----------------
// m97 structure (r2-exact, session-best): 128x128 tile, BK=64, unpadded LDS,
// global_load_lds width 16, NO XCD swizzle (r7: wrecks A-panel L2 reuse).
// VSTORE: blocks with n0>=2048 (V section of QKV) store transposed into vtout
//         [b][h][dv][l] as 8B packed bf16.

template <int OUT_F32, int RELU, int HASBIAS, int SPLITK, int SCALEQ, int VSTORE>
__global__ __launch_bounds__(256, 4) void gemm_bt(const u16* __restrict__ A,
                                                  const u16* __restrict__ Bt,
                                                  const float* __restrict__ bias,
                                                  void* __restrict__ Cout,
                                                  u16* __restrict__ vtout,
                                                  int M, int N, int K) {
    __shared__ __attribute__((aligned(16))) u16 As[128 * 64];
    __shared__ __attribute__((aligned(16))) u16 Bs[128 * 64];
    const int tid = threadIdx.x;
    const int lane = tid & 63, wid = tid >> 6;
    const int quad = lane >> 4, l16 = lane & 15;
    const int m0 = blockIdx.x * 128, n0 = blockIdx.y * 128;
    const int z = (SPLITK > 1) ? blockIdx.z : 0;
    const int Klen = K / SPLITK;
    const int kend = (z + 1) * Klen;
    const int wm = (wid >> 1) * 64, wn = (wid & 1) * 64;

    f32x4 acc[4][4];
#pragma unroll
    for (int i = 0; i < 4; i++)
#pragma unroll
        for (int j = 0; j < 4; j++) acc[i][j] = (f32x4){0.f, 0.f, 0.f, 0.f};

    const int srow = lane >> 3, scol = (lane & 7) * 8;

    for (int kb = z * Klen; kb < kend; kb += 64) {
#pragma unroll
        for (int p = 0; p < 4; p++) {
            int c = wid * 4 + p;
            int row = c * 8 + srow;
            gload_lds16(&A[(size_t)(m0 + row) * K + kb + scol], &As[c * 512]);
            gload_lds16(&Bt[(size_t)(n0 + row) * K + kb + scol], &Bs[c * 512]);
        }
        __syncthreads();
#pragma unroll
        for (int kh = 0; kh < 2; kh++) {
            bf16x8 af[4], bf[4];
#pragma unroll
            for (int t = 0; t < 4; t++) {
                af[t] = *(const bf16x8*)&As[(wm + t * 16 + l16) * 64 + kh * 32 + quad * 8];
                bf[t] = *(const bf16x8*)&Bs[(wn + t * 16 + l16) * 64 + kh * 32 + quad * 8];
            }
#pragma unroll
            for (int i = 0; i < 4; i++)
#pragma unroll
                for (int j = 0; j < 4; j++)
                    acc[i][j] = __builtin_amdgcn_mfma_f32_16x16x32_bf16(
                        af[i], bf[j], acc[i][j], 0, 0, 0);
        }
        __syncthreads();
    }

    if (VSTORE && n0 >= 2048) {
        // V section -> vtout[b][dv][l], dv = col-2048, 4 consecutive l per store
#pragma unroll
        for (int i = 0; i < 4; i++) {
            int row0 = m0 + wm + i * 16 + quad * 4;
            int bb = row0 >> 11, l = row0 & 2047;
#pragma unroll
            for (int j = 0; j < 4; j++) {
                int col = n0 + wn + j * 16 + l16;
                float bv = HASBIAS ? bias[col] : 0.f;
                int dv = col - 2048;
                u32x2 w;
                w.x = pack_bf2(acc[i][j][0] + bv, acc[i][j][1] + bv);
                w.y = pack_bf2(acc[i][j][2] + bv, acc[i][j][3] + bv);
                *(u32x2*)&vtout[((size_t)(bb * 1024 + dv)) * 2048 + l] = w;
            }
        }
        return;
    }

    float* outf = (float*)Cout + (size_t)z * M * N;
#pragma unroll
    for (int i = 0; i < 4; i++) {
#pragma unroll
        for (int j = 0; j < 4; j++) {
#pragma unroll
            for (int r = 0; r < 4; r++) {
                int row = m0 + wm + i * 16 + quad * 4 + r;
                int col = n0 + wn + j * 16 + l16;
                float v = acc[i][j][r];
                if (HASBIAS) v += bias[col];
                if (RELU) v = v > 0.f ? v : 0.f;
                if (SCALEQ && col < 1024) v *= Q_SCALE;
                if (OUT_F32)
                    outf[(size_t)row * N + col] = v;
                else
                    ((u16*)Cout)[(size_t)row * N + col] = f2bfraw(v);
            }
        }
    }
}

// ---------------- flash attention, S^T form, v4 -----------------------------
// grid (SEQ/128, NH, BATCH); 4 waves x 256 threads; wave owns 32 q rows
// (qt in {0,1} of 16 each).
// v4 vs v3: restore the x2 K/V fragment reuse of the 32-q-per-wave form —
// each kf/vf b128 read now feeds TWO MFMAs (one per qt), halving LDS-port
// traffic per FLOP (v3's 16q/wave read each frag once; LDS port was the
// co-bottleneck: ~32 b128/wave/tile x 16 waves/CU ~ 4096 cyc/tile vs 2560
// MFMA cyc over 4 pipes). Keeps v3's verified pieces unchanged:
//  - P never touches LDS (k-permute is per-16-q-column -> composes with qt),
//  - K double-buffered via gload_lds with pre-swizzled source,
//  - V reg-staged, k-permuted + swizzled.
// LDS = 2*16384 (K dbuf) + 16384 (V) = 49152 B; ~175 VGPR peak.
__global__ __launch_bounds__(256, 2) void attn_kernel(const u16* __restrict__ qkv,
                                                      const u16* __restrict__ vt,
                                                      u16* __restrict__ O) {
    __shared__ __attribute__((aligned(16))) u16 Ks[2][128 * 64]; // [k=128][dk=64], swz
    __shared__ __attribute__((aligned(16))) u16 Vs[64 * 128];    // [dv=64][k-permuted], swz

    const int tid = threadIdx.x;
    const int lane = tid & 63, wid = tid >> 6;
    const int quad = lane >> 4, l16 = lane & 15;
    const int sw = l16 & 7;  // row-swizzle key for all l16-row reads
    const int b = blockIdx.z, h = blockIdx.y;
    const int q0 = blockIdx.x * 128 + wid * 32;

    // Q fragments (B-operand: n=q=qt*16+l16, k=quad*8+j); Q pre-scaled
    bf16x8 qf[2][2];
#pragma unroll
    for (int qt = 0; qt < 2; qt++) {
        const size_t qrow = (size_t)(b * SEQ + q0 + qt * 16 + l16) * NQKV + h * DK;
        qf[qt][0] = *(const bf16x8*)&qkv[qrow + quad * 8];
        qf[qt][1] = *(const bf16x8*)&qkv[qrow + 32 + quad * 8];
    }

    const u16* Kbase = qkv + (size_t)(b * SEQ) * NQKV + D_MODEL + h * DK;
    const u16* Vbase = vt + (size_t)((b * NH + h) * DK) * SEQ;

    f32x4 oacc[4][2];
#pragma unroll
    for (int d = 0; d < 4; d++) {
        oacc[d][0] = (f32x4){0.f, 0.f, 0.f, 0.f};
        oacc[d][1] = (f32x4){0.f, 0.f, 0.f, 0.f};
    }
    float lr[2] = {0.f, 0.f};
    const f32x4 Z = {0.f, 0.f, 0.f, 0.f};

    // K tile stage: direct-to-LDS, source pre-swizzled (chunk ^ row&7).
    // 16 wave-groups of 1024B; group g = p*4+wid; lane element e = g*64+lane.
    auto stage_k = [&](int kt2, int buf) {
#pragma unroll
        for (int p = 0; p < 4; p++) {
            int g = p * 4 + wid;
            int row = g * 8 + (lane >> 3);
            int chunk = (lane & 7) ^ (lane >> 3);    // row&7 == lane>>3
            gload_lds16(&Kbase[(size_t)(kt2 + row) * NQKV + chunk * 8],
                        &Ks[buf][g * 512]);
        }
    };
    // V tile load to regs (reg-staged: permuted LDS write can't use gload_lds)
    bf16x8 vreg[4];
    auto load_v = [&](int kt2) {
#pragma unroll
        for (int p = 0; p < 4; p++) {
            int s = p * 256 + tid;
            vreg[p] = *(const bf16x8*)&Vbase[(size_t)(s >> 4) * SEQ + kt2 + (s & 15) * 8];
        }
    };
    stage_k(0, 0);
    load_v(0);

    for (int t = 0; t < SEQ / 128; t++) {
        const int kt = t * 128;
        // ---- write V(t) regs -> Vs, k-permuted + swizzled -------------------
#pragma unroll
        for (int p = 0; p < 4; p++) {
            int s = p * 256 + tid;
            int vr = s >> 4, vc = s & 15;
            int chunkA = (vc >> 2) * 4 + (vc & 1) * 2;
            int rem = ((vc >> 1) & 1) * 4;
            u32x4 kv = __builtin_bit_cast(u32x4, vreg[p]);
            *(u32x2*)&Vs[vr * 128 + ((chunkA ^ (vr & 7)) * 8) + rem] =
                (u32x2){kv.x, kv.y};
            *(u32x2*)&Vs[vr * 128 + (((chunkA + 1) ^ (vr & 7)) * 8) + rem] =
                (u32x2){kv.z, kv.w};
        }
        __syncthreads();  // K(t) landed (vmcnt drained), Vs visible to all waves

        // issue next tile's K-to-LDS + V-to-regs; drained at barrier2
        if (t + 1 < SEQ / 128) {
            stage_k(kt + 128, (t + 1) & 1);
            load_v(kt + 128);
        }

        const u16* kb = Ks[t & 1];

        // ---- S^T = K·Q^T : sacc[nt][qt]; kf reused across qt (x2) ----
        f32x4 sacc[8][2];
        __builtin_amdgcn_s_setprio(1);
#pragma unroll
        for (int nt = 0; nt < 8; nt++) {
            const u16* krow = &kb[(nt * 16 + l16) * 64];
            bf16x8 kf0 = *(const bf16x8*)&krow[(quad ^ sw) * 8];
            bf16x8 kf1 = *(const bf16x8*)&krow[((4 + quad) ^ sw) * 8];
#pragma unroll
            for (int qt = 0; qt < 2; qt++) {
                f32x4 s0 = __builtin_amdgcn_mfma_f32_16x16x32_bf16(kf0, qf[qt][0], Z, 0, 0, 0);
                sacc[nt][qt] = __builtin_amdgcn_mfma_f32_16x16x32_bf16(kf1, qf[qt][1], s0, 0, 0, 0);
            }
        }
        __builtin_amdgcn_s_setprio(0);

        // ---- softmax fully in-register: exp2, per-lane sum, pack bf16 ----
        u32 wreg[2][8][2];
#pragma unroll
        for (int qt = 0; qt < 2; qt++) {
#pragma unroll
            for (int nt = 0; nt < 8; nt++) {
                float p0 = __builtin_amdgcn_exp2f(sacc[nt][qt][0]);
                float p1 = __builtin_amdgcn_exp2f(sacc[nt][qt][1]);
                float p2 = __builtin_amdgcn_exp2f(sacc[nt][qt][2]);
                float p3 = __builtin_amdgcn_exp2f(sacc[nt][qt][3]);
                lr[qt] += (p0 + p1) + (p2 + p3);
                wreg[qt][nt][0] = pack_bf2(p0, p1);
                wreg[qt][nt][1] = pack_bf2(p2, p3);
            }
        }

        // ---- O^T += V^T·P^T over permuted k; vf reused across qt (x2) ----
        __builtin_amdgcn_s_setprio(1);
#pragma unroll
        for (int ks = 0; ks < 4; ks++) {
            bf16x8 pf[2];
#pragma unroll
            for (int qt = 0; qt < 2; qt++) {
                u32x4 pw = (u32x4){wreg[qt][2 * ks][0], wreg[qt][2 * ks][1],
                                   wreg[qt][2 * ks + 1][0], wreg[qt][2 * ks + 1][1]};
                pf[qt] = __builtin_bit_cast(bf16x8, pw);
            }
#pragma unroll
            for (int d = 0; d < 4; d++) {
                bf16x8 vf = *(const bf16x8*)&Vs[(d * 16 + l16) * 128 +
                                                (((ks * 4 + quad) ^ sw) * 8)];
                oacc[d][0] = __builtin_amdgcn_mfma_f32_16x16x32_bf16(vf, pf[0], oacc[d][0], 0, 0, 0);
                oacc[d][1] = __builtin_amdgcn_mfma_f32_16x16x32_bf16(vf, pf[1], oacc[d][1], 0, 0, 0);
            }
        }
        __builtin_amdgcn_s_setprio(0);
        __syncthreads();  // all waves done with Ks[t&1]/Vs before restage
    }

    // lane's lr covers its quad's 32 k's per tile; reduce across quads
#pragma unroll
    for (int qt = 0; qt < 2; qt++) {
        lr[qt] += __shfl_xor(lr[qt], 16, 64);
        lr[qt] += __shfl_xor(lr[qt], 32, 64);
    }

    // O^T C-layout: col=q=qt*16+l16, row=dv=d*16+quad*4+r -> b64 stores
#pragma unroll
    for (int qt = 0; qt < 2; qt++) {
        float iv = 1.f / lr[qt];
        size_t row = (size_t)(b * SEQ + q0 + qt * 16 + l16);
#pragma unroll
        for (int d = 0; d < 4; d++) {
            float o0 = oacc[d][qt][0] * iv, o1 = oacc[d][qt][1] * iv;
            float o2 = oacc[d][qt][2] * iv, o3 = oacc[d][qt][3] * iv;
            u32x2 w;
            w.x = ((u32)f2bfraw(o1) << 16) | f2bfraw(o0);
            w.y = ((u32)f2bfraw(o3) << 16) | f2bfraw(o2);
            *(u32x2*)&O[row * D_MODEL + h * DK + d * 16 + quad * 4] = w;
        }
    }
}

// ---------------- LayerNorm(a + b + c), f32 residual stream ----------------
__global__ __launch_bounds__(256) void ln3_kernel(const float* __restrict__ xa,
                                                  const float* __restrict__ xb,
                                                  const float* __restrict__ xc,
                                                  const float* __restrict__ g,
                                                  const float* __restrict__ be,
                                                  u16* __restrict__ out_bf,
                                                  float* __restrict__ out_f) {
    int row = blockIdx.x;
    int tid = threadIdx.x;
    const float* pa = xa + (size_t)row * D_MODEL;
    const float* pb = xb + (size_t)row * D_MODEL;
    const float* pc = xc + (size_t)row * D_MODEL;
    int c = tid * 4;
    f32x4 av = *(const f32x4*)&pa[c];
    f32x4 bv = *(const f32x4*)&pb[c];
    f32x4 cv = *(const f32x4*)&pc[c];
    float v[4];
    float s = 0.f, ss = 0.f;
#pragma unroll
    for (int i = 0; i < 4; i++) {
        v[i] = av[i] + bv[i] + cv[i];
        s += v[i];
        ss += v[i] * v[i];
    }
#pragma unroll
    for (int off = 32; off; off >>= 1) {
        s += __shfl_down(s, off, 64);
        ss += __shfl_down(ss, off, 64);
    }
    __shared__ float red[8];
    int wid = tid >> 6, lane = tid & 63;
    if (lane == 0) { red[wid] = s; red[4 + wid] = ss; }
    __syncthreads();
    if (tid == 0) {
        red[0] = red[0] + red[1] + red[2] + red[3];
        red[4] = red[4] + red[5] + red[6] + red[7];
    }
    __syncthreads();
    float mu = red[0] * (1.f / D_MODEL);
    float var = red[4] * (1.f / D_MODEL) - mu * mu;
    float rs = rsqrtf(var + 1e-5f);
#pragma unroll
    for (int i = 0; i < 4; i++) {
        float o = (v[i] - mu) * rs * g[c + i] + be[c + i];
        if (out_f) out_f[(size_t)row * D_MODEL + c + i] = o;
        if (out_bf) out_bf[(size_t)row * D_MODEL + c + i] = f2bfraw(o);
    }
}

// ---------------- launch ----------------
extern "C" void kernel_launch(void* const* d_in, const int* in_sizes, int n_in,
                              void* d_out, int out_size, void* d_ws, size_t ws_size,
                              hipStream_t stream) {
    const float* x   = (const float*)d_in[0];
    const float* Wq  = (const float*)d_in[1];
    const float* bq  = (const float*)d_in[2];
    const float* Wk  = (const float*)d_in[3];
    const float* bk  = (const float*)d_in[4];
    const float* Wv  = (const float*)d_in[5];
    const float* bv  = (const float*)d_in[6];
    const float* Wo  = (const float*)d_in[7];
    const float* g1  = (const float*)d_in[8];
    const float* be1 = (const float*)d_in[9];
    const float* W1  = (const float*)d_in[10];
    const float* b1  = (const float*)d_in[11];
    const float* W2  = (const float*)d_in[12];
    const float* g2  = (const float*)d_in[13];
    const float* be2 = (const float*)d_in[14];

    char* w = (char*)d_ws;
    auto alloc = [&](size_t bytes) {
        char* p = w;
        w += (bytes + 255) & ~(size_t)255;
        return p;
    };
    u16* wqkv_t = (u16*)alloc((size_t)NQKV * D_MODEL * 2);
    u16* wo_t   = (u16*)alloc((size_t)D_MODEL * D_MODEL * 2);
    u16* w1_t   = (u16*)alloc((size_t)DFF * D_MODEL * 2);
    u16* w2_t   = (u16*)alloc((size_t)D_MODEL * DFF * 2);
    float* bqkv = (float*)alloc((size_t)NQKV * 4);
    u16* x_bf   = (u16*)alloc((size_t)BL * D_MODEL * 2);
    u16* qkvbuf = (u16*)alloc((size_t)BL * NQKV * 2);
    u16* vtbuf  = (u16*)alloc((size_t)BATCH * NH * DK * SEQ * 2);
    u16* obuf   = (u16*)alloc((size_t)BL * D_MODEL * 2);
    float* mha_p = (float*)alloc((size_t)2 * BL * D_MODEL * 4);  // split-K partials
    u16* h1_bf  = (u16*)alloc((size_t)BL * D_MODEL * 2);
    float* h1_f = (float*)alloc((size_t)BL * D_MODEL * 4);
    u16* ffa    = (u16*)alloc((size_t)BL * DFF * 2);
    float* ffb_p = (float*)alloc((size_t)2 * BL * D_MODEL * 4); // split-K partials

    // merged prep: all weight transposes + bias concat + x cast (1 launch)
    prep_weights<<<dim3(1024, 1, 7), 256, 0, stream>>>(
        Wq, Wk, Wv, Wo, W1, W2, bq, bk, bv, x,
        wqkv_t, wo_t, w1_t, w2_t, bqkv, x_bf);

    // QKV = x @ Wqkv^T + bias -> Q,K bf16 into qkvbuf; V transposed into vtbuf
    gemm_bt<0, 0, 1, 1, 1, 1><<<dim3(32, 24), 256, 0, stream>>>(
        x_bf, wqkv_t, bqkv, qkvbuf, vtbuf, BL, NQKV, D_MODEL);
    // flash attention -> O bf16 [4096][1024]
    attn_kernel<<<dim3(16, 16, 2), 256, 0, stream>>>(qkvbuf, vtbuf, obuf);
    // mha partials = O @ Wo (split-K=2) -> f32 x2
    gemm_bt<1, 0, 0, 2, 0, 0><<<dim3(32, 8, 2), 256, 0, stream>>>(
        obuf, wo_t, nullptr, mha_p, nullptr, BL, D_MODEL, D_MODEL);
    // h1 = LN(x + mha_p0 + mha_p1)
    ln3_kernel<<<dim3(BL), 256, 0, stream>>>(x, mha_p, mha_p + (size_t)BL * D_MODEL,
                                             g1, be1, h1_bf, h1_f);
    // ffa = relu(h1 @ W1 + b1) -> bf16 [4096][4096]
    gemm_bt<0, 1, 1, 1, 0, 0><<<dim3(32, 32), 256, 0, stream>>>(
        h1_bf, w1_t, b1, ffa, nullptr, BL, DFF, D_MODEL);
    // ffb partials = ffa @ W2 (split-K=2) -> f32 x2
    gemm_bt<1, 0, 0, 2, 0, 0><<<dim3(32, 8, 2), 256, 0, stream>>>(
        ffa, w2_t, nullptr, ffb_p, nullptr, BL, D_MODEL, DFF);
    // out = LN(h1 + ffb_p0 + ffb_p1)
    ln3_kernel<<<dim3(BL), 256, 0, stream>>>(h1_f, ffb_p, ffb_p + (size_t)BL * D_MODEL,
                                             g2, be2, nullptr, (float*)d_out);
}

// Round 10
// 356.268 us; speedup vs baseline: 1.0303x; 1.0303x over previous
//
#include <hip/hip_runtime.h>

typedef unsigned short u16;
typedef unsigned int u32;
typedef short bf16x8 __attribute__((ext_vector_type(8)));
typedef float f32x4 __attribute__((ext_vector_type(4)));
typedef unsigned int u32x2 __attribute__((ext_vector_type(2)));
typedef unsigned int u32x4 __attribute__((ext_vector_type(4)));

#define D_MODEL 1024
#define NH 16
#define DK 64
#define DFF 4096
#define BATCH 2
#define SEQ 2048
#define BL (BATCH*SEQ)
#define NQKV 3072
// fold (1/sqrt(64)) * log2(e) into Q so softmax is raw exp2 (v_exp_f32)
#define Q_SCALE 0.18033688011f

__device__ __forceinline__ float bfraw2f(u16 u) {
    union { u32 i; float f; } c; c.i = ((u32)u) << 16; return c.f;
}
__device__ __forceinline__ u16 f2bfraw(float f) {
    union { float f; u32 i; } c; c.f = f;
    u32 i = c.i;
    u32 lsb = (i >> 16) & 1u;
    i += 0x7fffu + lsb;
    return (u16)(i >> 16);
}
__device__ __forceinline__ u32 fasu(float f) {
    union { float f; u32 i; } c; c.f = f; return c.i;
}
// pack two f32 -> (bf16(hi)<<16)|bf16(lo), round-to-nearest via +0x8000
__device__ __forceinline__ u32 pack_bf2(float lo, float hi) {
    return __builtin_amdgcn_perm(fasu(hi) + 0x8000u, fasu(lo) + 0x8000u,
                                 0x07060302u);
}
// async global->LDS 16B per lane (dest = wave-uniform base + lane*16)
__device__ __forceinline__ void gload_lds16(const u16* g, u16* l) {
    __builtin_amdgcn_global_load_lds(
        (const __attribute__((address_space(1))) void*)g,
        (__attribute__((address_space(3))) void*)l, 16, 0, 0);
}

// ---------------- merged prep: weight transposes + bias concat + x cast -----
// grid (1024, 1, 7), 256 thr.
// z=0..2: Wq/Wk/Wv per-head transpose into fused [3072][1024] B^T layout
//         (z=0 blocks 256..267 also do the bias concat).
// z=3: Wo (1024x1024). z=4: W1 (1024x4096). z=5: W2 (4096x1024).
// z=6: x f32 -> bf16 cast, 4 chunks per block.
__global__ __launch_bounds__(256) void prep_weights(
    const float* __restrict__ Wq, const float* __restrict__ Wk,
    const float* __restrict__ Wv, const float* __restrict__ Wo,
    const float* __restrict__ W1, const float* __restrict__ W2,
    const float* __restrict__ bq, const float* __restrict__ bk,
    const float* __restrict__ bv, const float* __restrict__ x,
    u16* __restrict__ wqkv_t, u16* __restrict__ wo_t,
    u16* __restrict__ w1_t, u16* __restrict__ w2_t,
    float* __restrict__ bqkv, u16* __restrict__ x_bf) {
    __shared__ u16 t[64][65];
    const int z = blockIdx.z, bx = blockIdx.x;
    const int col = threadIdx.x & 63, rr = threadIdx.x >> 6;

    if (z == 6) {
        // cast x: 4096*1024 f32 -> bf16; 1024 blocks x 4 chunks x 1024 elems
#pragma unroll
        for (int j = 0; j < 4; j++) {
            int i = (((j << 10) + bx) * 256 + threadIdx.x) * 4;
            f32x4 v = *(const f32x4*)&x[i];
#pragma unroll
            for (int e = 0; e < 4; e++) x_bf[i + e] = f2bfraw(v[e]);
        }
        return;
    }

    if (z < 3) {
        if (bx >= 256) {
            if (z == 0 && bx < 268) {
                int i = (bx - 256) * 256 + threadIdx.x;
                bqkv[i] = (i < 1024) ? bq[i]
                        : (i < 2048) ? bk[i - 1024] : bv[i - 2048];
            }
            return;
        }
        const int d0 = (bx & 15) * 64, h = bx >> 4;
        const float* W = (z == 0) ? Wq : (z == 1) ? Wk : Wv;
        const float* src = W + (size_t)h * D_MODEL * DK;
        for (int i = rr; i < 64; i += 4)
            t[i][col] = f2bfraw(src[(size_t)(d0 + i) * DK + col]);
        __syncthreads();
        u16* dst = wqkv_t + (size_t)(z * 1024 + h * 64) * D_MODEL;
        for (int i = rr; i < 64; i += 4)
            dst[(size_t)i * D_MODEL + d0 + col] = t[col][i];
        return;
    }

    const float* in; u16* out; int R, C;
    if (z == 3)      { in = Wo; out = wo_t; R = 1024; C = 1024; }
    else if (z == 4) { in = W1; out = w1_t; R = 1024; C = 4096; }
    else             { in = W2; out = w2_t; R = 4096; C = 1024; }
    const int ctiles = C >> 6;
    const int rt = bx / ctiles, ct = bx % ctiles;
    if (rt >= (R >> 6)) return;
    const int c0 = ct * 64, r0 = rt * 64;
    for (int i = rr; i < 64; i += 4)
        t[i][col] = f2bfraw(in[(size_t)(r0 + i) * C + c0 + col]);
    __syncthreads();
    for (int i = rr; i < 64; i += 4)
        out[(size_t)(c0 + i) * R + r0 + col] = t[col][i];
}

// ---------------- GEMM: C[M][N] = A[M][K] @ Bt[N][K]^T ----------------
// m97 structure (r2-exact, session-best): 128x128 tile, BK=64, unpadded LDS,
// global_load_lds width 16, NO XCD swizzle (r7: wrecks A-panel L2 reuse).
// VSTORE: blocks with n0>=2048 (V section of QKV) store transposed into vtout
//         [b][h][dv][l] as 8B packed bf16.

template <int OUT_F32, int RELU, int HASBIAS, int SPLITK, int SCALEQ, int VSTORE>
__global__ __launch_bounds__(256, 4) void gemm_bt(const u16* __restrict__ A,
                                                  const u16* __restrict__ Bt,
                                                  const float* __restrict__ bias,
                                                  void* __restrict__ Cout,
                                                  u16* __restrict__ vtout,
                                                  int M, int N, int K) {
    __shared__ __attribute__((aligned(16))) u16 As[128 * 64];
    __shared__ __attribute__((aligned(16))) u16 Bs[128 * 64];
    const int tid = threadIdx.x;
    const int lane = tid & 63, wid = tid >> 6;
    const int quad = lane >> 4, l16 = lane & 15;
    const int m0 = blockIdx.x * 128, n0 = blockIdx.y * 128;
    const int z = (SPLITK > 1) ? blockIdx.z : 0;
    const int Klen = K / SPLITK;
    const int kend = (z + 1) * Klen;
    const int wm = (wid >> 1) * 64, wn = (wid & 1) * 64;

    f32x4 acc[4][4];
#pragma unroll
    for (int i = 0; i < 4; i++)
#pragma unroll
        for (int j = 0; j < 4; j++) acc[i][j] = (f32x4){0.f, 0.f, 0.f, 0.f};

    const int srow = lane >> 3, scol = (lane & 7) * 8;

    for (int kb = z * Klen; kb < kend; kb += 64) {
#pragma unroll
        for (int p = 0; p < 4; p++) {
            int c = wid * 4 + p;
            int row = c * 8 + srow;
            gload_lds16(&A[(size_t)(m0 + row) * K + kb + scol], &As[c * 512]);
            gload_lds16(&Bt[(size_t)(n0 + row) * K + kb + scol], &Bs[c * 512]);
        }
        __syncthreads();
#pragma unroll
        for (int kh = 0; kh < 2; kh++) {
            bf16x8 af[4], bf[4];
#pragma unroll
            for (int t = 0; t < 4; t++) {
                af[t] = *(const bf16x8*)&As[(wm + t * 16 + l16) * 64 + kh * 32 + quad * 8];
                bf[t] = *(const bf16x8*)&Bs[(wn + t * 16 + l16) * 64 + kh * 32 + quad * 8];
            }
#pragma unroll
            for (int i = 0; i < 4; i++)
#pragma unroll
                for (int j = 0; j < 4; j++)
                    acc[i][j] = __builtin_amdgcn_mfma_f32_16x16x32_bf16(
                        af[i], bf[j], acc[i][j], 0, 0, 0);
        }
        __syncthreads();
    }

    if (VSTORE && n0 >= 2048) {
        // V section -> vtout[b][dv][l], dv = col-2048, 4 consecutive l per store
#pragma unroll
        for (int i = 0; i < 4; i++) {
            int row0 = m0 + wm + i * 16 + quad * 4;
            int bb = row0 >> 11, l = row0 & 2047;
#pragma unroll
            for (int j = 0; j < 4; j++) {
                int col = n0 + wn + j * 16 + l16;
                float bv = HASBIAS ? bias[col] : 0.f;
                int dv = col - 2048;
                u32x2 w;
                w.x = pack_bf2(acc[i][j][0] + bv, acc[i][j][1] + bv);
                w.y = pack_bf2(acc[i][j][2] + bv, acc[i][j][3] + bv);
                *(u32x2*)&vtout[((size_t)(bb * 1024 + dv)) * 2048 + l] = w;
            }
        }
        return;
    }

    float* outf = (float*)Cout + (size_t)z * M * N;
#pragma unroll
    for (int i = 0; i < 4; i++) {
#pragma unroll
        for (int j = 0; j < 4; j++) {
#pragma unroll
            for (int r = 0; r < 4; r++) {
                int row = m0 + wm + i * 16 + quad * 4 + r;
                int col = n0 + wn + j * 16 + l16;
                float v = acc[i][j][r];
                if (HASBIAS) v += bias[col];
                if (RELU) v = v > 0.f ? v : 0.f;
                if (SCALEQ && col < 1024) v *= Q_SCALE;
                if (OUT_F32)
                    outf[(size_t)row * N + col] = v;
                else
                    ((u16*)Cout)[(size_t)row * N + col] = f2bfraw(v);
            }
        }
    }
}

// ---------------- flash attention, S^T form, v3 (r3-exact, session-best) ----
// grid (SEQ/128, NH, BATCH); 8 waves x 512 threads; wave owns 16 q rows.
//  - P never touches LDS: PV's k-axis permuted per 32-slice (pi bijective),
//    V stored pre-permuted so PV B-frag = lane-local packed exp() output.
//  - K double-buffered via global_load_lds with pre-swizzled source.
//  - LDS = 2*16384 (K dbuf) + 16384 (V) = 49152 B; 16 waves/CU.
__global__ __launch_bounds__(512, 4) void attn_kernel(const u16* __restrict__ qkv,
                                                      const u16* __restrict__ vt,
                                                      u16* __restrict__ O) {
    __shared__ __attribute__((aligned(16))) u16 Ks[2][128 * 64]; // [k=128][dk=64], swz
    __shared__ __attribute__((aligned(16))) u16 Vs[64 * 128];    // [dv=64][k-permuted], swz

    const int tid = threadIdx.x;
    const int lane = tid & 63, wid = tid >> 6;
    const int quad = lane >> 4, l16 = lane & 15;
    const int sw = l16 & 7;  // row-swizzle key for all l16-row reads
    const int b = blockIdx.z, h = blockIdx.y;
    const int q0 = blockIdx.x * 128 + wid * 16;

    // Q fragments (B-operand: n=q=l16, k=quad*8+j); Q pre-scaled by Q_SCALE
    const size_t qrow = (size_t)(b * SEQ + q0 + l16) * NQKV + h * DK;
    const bf16x8 qf0 = *(const bf16x8*)&qkv[qrow + quad * 8];
    const bf16x8 qf1 = *(const bf16x8*)&qkv[qrow + 32 + quad * 8];

    const u16* Kbase = qkv + (size_t)(b * SEQ) * NQKV + D_MODEL + h * DK;
    const u16* Vbase = vt + (size_t)((b * NH + h) * DK) * SEQ;

    f32x4 oacc[4];
#pragma unroll
    for (int d = 0; d < 4; d++) oacc[d] = (f32x4){0.f, 0.f, 0.f, 0.f};
    float lr = 0.f;
    const f32x4 Z = {0.f, 0.f, 0.f, 0.f};

    // K tile stage: direct-to-LDS, source pre-swizzled (chunk ^ row&7)
    auto stage_k = [&](int kt2, int buf) {
#pragma unroll
        for (int p = 0; p < 2; p++) {
            int seg = p * 8 + wid;                   // 16 segments of 8 rows
            int row = seg * 8 + (lane >> 3);
            int chunk = (lane & 7) ^ (lane >> 3);    // row&7 == lane>>3
            gload_lds16(&Kbase[(size_t)(kt2 + row) * NQKV + chunk * 8],
                        &Ks[buf][seg * 512]);
        }
    };
    // V tile load to regs (reg-staged: permuted LDS write can't use gload_lds)
    bf16x8 vreg[2];
    auto load_v = [&](int kt2) {
#pragma unroll
        for (int p = 0; p < 2; p++) {
            int s = p * 512 + tid;
            vreg[p] = *(const bf16x8*)&Vbase[(size_t)(s >> 4) * SEQ + kt2 + (s & 15) * 8];
        }
    };
    stage_k(0, 0);
    load_v(0);

    for (int t = 0; t < SEQ / 128; t++) {
        const int kt = t * 128;
        // ---- write V(t) regs -> Vs, k-permuted + swizzled -------------------
#pragma unroll
        for (int p = 0; p < 2; p++) {
            int s = p * 512 + tid;
            int vr = s >> 4, vc = s & 15;
            int chunkA = (vc >> 2) * 4 + (vc & 1) * 2;
            int rem = ((vc >> 1) & 1) * 4;
            u32x4 kv = __builtin_bit_cast(u32x4, vreg[p]);
            *(u32x2*)&Vs[vr * 128 + ((chunkA ^ (vr & 7)) * 8) + rem] =
                (u32x2){kv.x, kv.y};
            *(u32x2*)&Vs[vr * 128 + (((chunkA + 1) ^ (vr & 7)) * 8) + rem] =
                (u32x2){kv.z, kv.w};
        }
        __syncthreads();  // K(t) landed (vmcnt drained), Vs visible to all waves

        // issue next tile's K-to-LDS + V-to-regs; drained at barrier2
        if (t + 1 < SEQ / 128) {
            stage_k(kt + 128, (t + 1) & 1);
            load_v(kt + 128);
        }

        const u16* kb = Ks[t & 1];

        // ---- S^T = K·Q^T : sacc[nt], k=nt*16+quad*4+r, q=l16 ----
        f32x4 sacc[8];
        __builtin_amdgcn_s_setprio(1);
#pragma unroll
        for (int nt = 0; nt < 8; nt++) {
            const u16* krow = &kb[(nt * 16 + l16) * 64];
            bf16x8 kf0 = *(const bf16x8*)&krow[(quad ^ sw) * 8];
            bf16x8 kf1 = *(const bf16x8*)&krow[((4 + quad) ^ sw) * 8];
            f32x4 s0 = __builtin_amdgcn_mfma_f32_16x16x32_bf16(kf0, qf0, Z, 0, 0, 0);
            sacc[nt] = __builtin_amdgcn_mfma_f32_16x16x32_bf16(kf1, qf1, s0, 0, 0, 0);
        }
        __builtin_amdgcn_s_setprio(0);

        // ---- softmax fully in-register: exp2, per-lane sum, pack bf16 ----
        u32 wreg[8][2];
#pragma unroll
        for (int nt = 0; nt < 8; nt++) {
            float p0 = __builtin_amdgcn_exp2f(sacc[nt][0]);
            float p1 = __builtin_amdgcn_exp2f(sacc[nt][1]);
            float p2 = __builtin_amdgcn_exp2f(sacc[nt][2]);
            float p3 = __builtin_amdgcn_exp2f(sacc[nt][3]);
            lr += (p0 + p1) + (p2 + p3);
            wreg[nt][0] = pack_bf2(p0, p1);
            wreg[nt][1] = pack_bf2(p2, p3);
        }

        // ---- O^T += V^T·P^T over permuted k: B-frag is lane-local ----
        __builtin_amdgcn_s_setprio(1);
#pragma unroll
        for (int ks = 0; ks < 4; ks++) {
            u32x4 pw = (u32x4){wreg[2 * ks][0], wreg[2 * ks][1],
                               wreg[2 * ks + 1][0], wreg[2 * ks + 1][1]};
            bf16x8 pf = __builtin_bit_cast(bf16x8, pw);
#pragma unroll
            for (int d = 0; d < 4; d++) {
                bf16x8 vf = *(const bf16x8*)&Vs[(d * 16 + l16) * 128 +
                                                (((ks * 4 + quad) ^ sw) * 8)];
                oacc[d] = __builtin_amdgcn_mfma_f32_16x16x32_bf16(vf, pf, oacc[d], 0, 0, 0);
            }
        }
        __builtin_amdgcn_s_setprio(0);
        __syncthreads();  // all waves done with Ks[t&1]/Vs before restage
    }

    // lane's lr covers its quad's 32 k's per tile; reduce across quads
    lr += __shfl_xor(lr, 16, 64);
    lr += __shfl_xor(lr, 32, 64);
    float iv = 1.f / lr;

    // O^T C-layout: col=q=l16, row=dv=d*16+quad*4+r -> b64 stores
    size_t row = (size_t)(b * SEQ + q0 + l16);
#pragma unroll
    for (int d = 0; d < 4; d++) {
        float o0 = oacc[d][0] * iv, o1 = oacc[d][1] * iv;
        float o2 = oacc[d][2] * iv, o3 = oacc[d][3] * iv;
        u32x2 w;
        w.x = ((u32)f2bfraw(o1) << 16) | f2bfraw(o0);
        w.y = ((u32)f2bfraw(o3) << 16) | f2bfraw(o2);
        *(u32x2*)&O[row * D_MODEL + h * DK + d * 16 + quad * 4] = w;
    }
}

// ---------------- LayerNorm(a + b + c), f32 residual stream ----------------
__global__ __launch_bounds__(256) void ln3_kernel(const float* __restrict__ xa,
                                                  const float* __restrict__ xb,
                                                  const float* __restrict__ xc,
                                                  const float* __restrict__ g,
                                                  const float* __restrict__ be,
                                                  u16* __restrict__ out_bf,
                                                  float* __restrict__ out_f) {
    int row = blockIdx.x;
    int tid = threadIdx.x;
    const float* pa = xa + (size_t)row * D_MODEL;
    const float* pb = xb + (size_t)row * D_MODEL;
    const float* pc = xc + (size_t)row * D_MODEL;
    int c = tid * 4;
    f32x4 av = *(const f32x4*)&pa[c];
    f32x4 bv = *(const f32x4*)&pb[c];
    f32x4 cv = *(const f32x4*)&pc[c];
    float v[4];
    float s = 0.f, ss = 0.f;
#pragma unroll
    for (int i = 0; i < 4; i++) {
        v[i] = av[i] + bv[i] + cv[i];
        s += v[i];
        ss += v[i] * v[i];
    }
#pragma unroll
    for (int off = 32; off; off >>= 1) {
        s += __shfl_down(s, off, 64);
        ss += __shfl_down(ss, off, 64);
    }
    __shared__ float red[8];
    int wid = tid >> 6, lane = tid & 63;
    if (lane == 0) { red[wid] = s; red[4 + wid] = ss; }
    __syncthreads();
    if (tid == 0) {
        red[0] = red[0] + red[1] + red[2] + red[3];
        red[4] = red[4] + red[5] + red[6] + red[7];
    }
    __syncthreads();
    float mu = red[0] * (1.f / D_MODEL);
    float var = red[4] * (1.f / D_MODEL) - mu * mu;
    float rs = rsqrtf(var + 1e-5f);
#pragma unroll
    for (int i = 0; i < 4; i++) {
        float o = (v[i] - mu) * rs * g[c + i] + be[c + i];
        if (out_f) out_f[(size_t)row * D_MODEL + c + i] = o;
        if (out_bf) out_bf[(size_t)row * D_MODEL + c + i] = f2bfraw(o);
    }
}

// ---------------- launch ----------------
extern "C" void kernel_launch(void* const* d_in, const int* in_sizes, int n_in,
                              void* d_out, int out_size, void* d_ws, size_t ws_size,
                              hipStream_t stream) {
    const float* x   = (const float*)d_in[0];
    const float* Wq  = (const float*)d_in[1];
    const float* bq  = (const float*)d_in[2];
    const float* Wk  = (const float*)d_in[3];
    const float* bk  = (const float*)d_in[4];
    const float* Wv  = (const float*)d_in[5];
    const float* bv  = (const float*)d_in[6];
    const float* Wo  = (const float*)d_in[7];
    const float* g1  = (const float*)d_in[8];
    const float* be1 = (const float*)d_in[9];
    const float* W1  = (const float*)d_in[10];
    const float* b1  = (const float*)d_in[11];
    const float* W2  = (const float*)d_in[12];
    const float* g2  = (const float*)d_in[13];
    const float* be2 = (const float*)d_in[14];

    char* w = (char*)d_ws;
    auto alloc = [&](size_t bytes) {
        char* p = w;
        w += (bytes + 255) & ~(size_t)255;
        return p;
    };
    u16* wqkv_t = (u16*)alloc((size_t)NQKV * D_MODEL * 2);
    u16* wo_t   = (u16*)alloc((size_t)D_MODEL * D_MODEL * 2);
    u16* w1_t   = (u16*)alloc((size_t)DFF * D_MODEL * 2);
    u16* w2_t   = (u16*)alloc((size_t)D_MODEL * DFF * 2);
    float* bqkv = (float*)alloc((size_t)NQKV * 4);
    u16* x_bf   = (u16*)alloc((size_t)BL * D_MODEL * 2);
    u16* qkvbuf = (u16*)alloc((size_t)BL * NQKV * 2);
    u16* vtbuf  = (u16*)alloc((size_t)BATCH * NH * DK * SEQ * 2);
    u16* obuf   = (u16*)alloc((size_t)BL * D_MODEL * 2);
    float* mha_p = (float*)alloc((size_t)2 * BL * D_MODEL * 4);  // split-K partials
    u16* h1_bf  = (u16*)alloc((size_t)BL * D_MODEL * 2);
    float* h1_f = (float*)alloc((size_t)BL * D_MODEL * 4);
    u16* ffa    = (u16*)alloc((size_t)BL * DFF * 2);
    float* ffb_p = (float*)alloc((size_t)2 * BL * D_MODEL * 4); // split-K partials

    // merged prep: all weight transposes + bias concat + x cast (1 launch)
    prep_weights<<<dim3(1024, 1, 7), 256, 0, stream>>>(
        Wq, Wk, Wv, Wo, W1, W2, bq, bk, bv, x,
        wqkv_t, wo_t, w1_t, w2_t, bqkv, x_bf);

    // QKV = x @ Wqkv^T + bias -> Q,K bf16 into qkvbuf; V transposed into vtbuf
    gemm_bt<0, 0, 1, 1, 1, 1><<<dim3(32, 24), 256, 0, stream>>>(
        x_bf, wqkv_t, bqkv, qkvbuf, vtbuf, BL, NQKV, D_MODEL);
    // flash attention -> O bf16 [4096][1024]
    attn_kernel<<<dim3(16, 16, 2), 512, 0, stream>>>(qkvbuf, vtbuf, obuf);
    // mha partials = O @ Wo (split-K=2) -> f32 x2
    gemm_bt<1, 0, 0, 2, 0, 0><<<dim3(32, 8, 2), 256, 0, stream>>>(
        obuf, wo_t, nullptr, mha_p, nullptr, BL, D_MODEL, D_MODEL);
    // h1 = LN(x + mha_p0 + mha_p1)
    ln3_kernel<<<dim3(BL), 256, 0, stream>>>(x, mha_p, mha_p + (size_t)BL * D_MODEL,
                                             g1, be1, h1_bf, h1_f);
    // ffa = relu(h1 @ W1 + b1) -> bf16 [4096][4096]
    gemm_bt<0, 1, 1, 1, 0, 0><<<dim3(32, 32), 256, 0, stream>>>(
        h1_bf, w1_t, b1, ffa, nullptr, BL, DFF, D_MODEL);
    // ffb partials = ffa @ W2 (split-K=2) -> f32 x2
    gemm_bt<1, 0, 0, 2, 0, 0><<<dim3(32, 8, 2), 256, 0, stream>>>(
        ffa, w2_t, nullptr, ffb_p, nullptr, BL, D_MODEL, DFF);
    // out = LN(h1 + ffb_p0 + ffb_p1)
    ln3_kernel<<<dim3(BL), 256, 0, stream>>>(h1_f, ffb_p, ffb_p + (size_t)BL * D_MODEL,
                                             g2, be2, nullptr, (float*)d_out);
}

// Round 11
// 355.800 us; speedup vs baseline: 1.0317x; 1.0013x over previous
//
#include <hip/hip_runtime.h>

typedef unsigned short u16;
typedef unsigned int u32;
typedef short bf16x8 __attribute__((ext_vector_type(8)));
typedef float f32x4 __attribute__((ext_vector_type(4)));
typedef unsigned int u32x2 __attribute__((ext_vector_type(2)));
typedef unsigned int u32x4 __attribute__((ext_vector_type(4)));

#define D_MODEL 1024
#define NH 16
#define DK 64
#define DFF 4096
#define BATCH 2
#define SEQ 2048
#define BL (BATCH*SEQ)
#define NQKV 3072
// fold (1/sqrt(64)) * log2(e) into Q so softmax is raw exp2 (v_exp_f32)
#define Q_SCALE 0.18033688011f

__device__ __forceinline__ float bfraw2f(u16 u) {
    union { u32 i; float f; } c; c.i = ((u32)u) << 16; return c.f;
}
__device__ __forceinline__ u16 f2bfraw(float f) {
    union { float f; u32 i; } c; c.f = f;
    u32 i = c.i;
    u32 lsb = (i >> 16) & 1u;
    i += 0x7fffu + lsb;
    return (u16)(i >> 16);
}
__device__ __forceinline__ u32 fasu(float f) {
    union { float f; u32 i; } c; c.f = f; return c.i;
}
// pack two f32 -> (bf16(hi)<<16)|bf16(lo), round-to-nearest via +0x8000
__device__ __forceinline__ u32 pack_bf2(float lo, float hi) {
    return __builtin_amdgcn_perm(fasu(hi) + 0x8000u, fasu(lo) + 0x8000u,
                                 0x07060302u);
}
// async global->LDS 16B per lane (dest = wave-uniform base + lane*16)
__device__ __forceinline__ void gload_lds16(const u16* g, u16* l) {
    __builtin_amdgcn_global_load_lds(
        (const __attribute__((address_space(1))) void*)g,
        (__attribute__((address_space(3))) void*)l, 16, 0, 0);
}

// ---------------- merged prep: weight transposes + bias concat + x cast -----
// grid (1024, 1, 7), 256 thr.
// z=0..2: Wq/Wk/Wv per-head transpose into fused [3072][1024] B^T layout
//         (z=0 blocks 256..267 also do the bias concat).
// z=3: Wo (1024x1024). z=4: W1 (1024x4096). z=5: W2 (4096x1024).
// z=6: x f32 -> bf16 cast, 4 chunks per block.
__global__ __launch_bounds__(256) void prep_weights(
    const float* __restrict__ Wq, const float* __restrict__ Wk,
    const float* __restrict__ Wv, const float* __restrict__ Wo,
    const float* __restrict__ W1, const float* __restrict__ W2,
    const float* __restrict__ bq, const float* __restrict__ bk,
    const float* __restrict__ bv, const float* __restrict__ x,
    u16* __restrict__ wqkv_t, u16* __restrict__ wo_t,
    u16* __restrict__ w1_t, u16* __restrict__ w2_t,
    float* __restrict__ bqkv, u16* __restrict__ x_bf) {
    __shared__ u16 t[64][65];
    const int z = blockIdx.z, bx = blockIdx.x;
    const int col = threadIdx.x & 63, rr = threadIdx.x >> 6;

    if (z == 6) {
        // cast x: 4096*1024 f32 -> bf16; 1024 blocks x 4 chunks x 1024 elems
#pragma unroll
        for (int j = 0; j < 4; j++) {
            int i = (((j << 10) + bx) * 256 + threadIdx.x) * 4;
            f32x4 v = *(const f32x4*)&x[i];
#pragma unroll
            for (int e = 0; e < 4; e++) x_bf[i + e] = f2bfraw(v[e]);
        }
        return;
    }

    if (z < 3) {
        if (bx >= 256) {
            if (z == 0 && bx < 268) {
                int i = (bx - 256) * 256 + threadIdx.x;
                bqkv[i] = (i < 1024) ? bq[i]
                        : (i < 2048) ? bk[i - 1024] : bv[i - 2048];
            }
            return;
        }
        const int d0 = (bx & 15) * 64, h = bx >> 4;
        const float* W = (z == 0) ? Wq : (z == 1) ? Wk : Wv;
        const float* src = W + (size_t)h * D_MODEL * DK;
        for (int i = rr; i < 64; i += 4)
            t[i][col] = f2bfraw(src[(size_t)(d0 + i) * DK + col]);
        __syncthreads();
        u16* dst = wqkv_t + (size_t)(z * 1024 + h * 64) * D_MODEL;
        for (int i = rr; i < 64; i += 4)
            dst[(size_t)i * D_MODEL + d0 + col] = t[col][i];
        return;
    }

    const float* in; u16* out; int R, C;
    if (z == 3)      { in = Wo; out = wo_t; R = 1024; C = 1024; }
    else if (z == 4) { in = W1; out = w1_t; R = 1024; C = 4096; }
    else             { in = W2; out = w2_t; R = 4096; C = 1024; }
    const int ctiles = C >> 6;
    const int rt = bx / ctiles, ct = bx % ctiles;
    if (rt >= (R >> 6)) return;
    const int c0 = ct * 64, r0 = rt * 64;
    for (int i = rr; i < 64; i += 4)
        t[i][col] = f2bfraw(in[(size_t)(r0 + i) * C + c0 + col]);
    __syncthreads();
    for (int i = rr; i < 64; i += 4)
        out[(size_t)(c0 + i) * R + r0 + col] = t[col][i];
}

// ---------------- GEMM: C[M][N] = A[M][K] @ Bt[N][K]^T ----------------
// m97 structure (r2-exact, session-best): 128x128 tile, BK=64, unpadded LDS,
// global_load_lds width 16, NO XCD swizzle (r7: wrecks A-panel L2 reuse).
// r11: bf16 output path now carries the split-K z-offset -> split-K partials
// can be bf16 (halves partial traffic; enables split-K=4 at neutral bytes).
// VSTORE: blocks with n0>=2048 (V section of QKV) store transposed into vtout
//         [b][h][dv][l] as 8B packed bf16.

template <int OUT_F32, int RELU, int HASBIAS, int SPLITK, int SCALEQ, int VSTORE>
__global__ __launch_bounds__(256, 4) void gemm_bt(const u16* __restrict__ A,
                                                  const u16* __restrict__ Bt,
                                                  const float* __restrict__ bias,
                                                  void* __restrict__ Cout,
                                                  u16* __restrict__ vtout,
                                                  int M, int N, int K) {
    __shared__ __attribute__((aligned(16))) u16 As[128 * 64];
    __shared__ __attribute__((aligned(16))) u16 Bs[128 * 64];
    const int tid = threadIdx.x;
    const int lane = tid & 63, wid = tid >> 6;
    const int quad = lane >> 4, l16 = lane & 15;
    const int m0 = blockIdx.x * 128, n0 = blockIdx.y * 128;
    const int z = (SPLITK > 1) ? blockIdx.z : 0;
    const int Klen = K / SPLITK;
    const int kend = (z + 1) * Klen;
    const int wm = (wid >> 1) * 64, wn = (wid & 1) * 64;

    f32x4 acc[4][4];
#pragma unroll
    for (int i = 0; i < 4; i++)
#pragma unroll
        for (int j = 0; j < 4; j++) acc[i][j] = (f32x4){0.f, 0.f, 0.f, 0.f};

    const int srow = lane >> 3, scol = (lane & 7) * 8;

    for (int kb = z * Klen; kb < kend; kb += 64) {
#pragma unroll
        for (int p = 0; p < 4; p++) {
            int c = wid * 4 + p;
            int row = c * 8 + srow;
            gload_lds16(&A[(size_t)(m0 + row) * K + kb + scol], &As[c * 512]);
            gload_lds16(&Bt[(size_t)(n0 + row) * K + kb + scol], &Bs[c * 512]);
        }
        __syncthreads();
#pragma unroll
        for (int kh = 0; kh < 2; kh++) {
            bf16x8 af[4], bf[4];
#pragma unroll
            for (int t = 0; t < 4; t++) {
                af[t] = *(const bf16x8*)&As[(wm + t * 16 + l16) * 64 + kh * 32 + quad * 8];
                bf[t] = *(const bf16x8*)&Bs[(wn + t * 16 + l16) * 64 + kh * 32 + quad * 8];
            }
#pragma unroll
            for (int i = 0; i < 4; i++)
#pragma unroll
                for (int j = 0; j < 4; j++)
                    acc[i][j] = __builtin_amdgcn_mfma_f32_16x16x32_bf16(
                        af[i], bf[j], acc[i][j], 0, 0, 0);
        }
        __syncthreads();
    }

    if (VSTORE && n0 >= 2048) {
        // V section -> vtout[b][dv][l], dv = col-2048, 4 consecutive l per store
#pragma unroll
        for (int i = 0; i < 4; i++) {
            int row0 = m0 + wm + i * 16 + quad * 4;
            int bb = row0 >> 11, l = row0 & 2047;
#pragma unroll
            for (int j = 0; j < 4; j++) {
                int col = n0 + wn + j * 16 + l16;
                float bv = HASBIAS ? bias[col] : 0.f;
                int dv = col - 2048;
                u32x2 w;
                w.x = pack_bf2(acc[i][j][0] + bv, acc[i][j][1] + bv);
                w.y = pack_bf2(acc[i][j][2] + bv, acc[i][j][3] + bv);
                *(u32x2*)&vtout[((size_t)(bb * 1024 + dv)) * 2048 + l] = w;
            }
        }
        return;
    }

    float* outf = (float*)Cout + (size_t)z * M * N;
    u16* outh = (u16*)Cout + (size_t)z * M * N;
#pragma unroll
    for (int i = 0; i < 4; i++) {
#pragma unroll
        for (int j = 0; j < 4; j++) {
#pragma unroll
            for (int r = 0; r < 4; r++) {
                int row = m0 + wm + i * 16 + quad * 4 + r;
                int col = n0 + wn + j * 16 + l16;
                float v = acc[i][j][r];
                if (HASBIAS) v += bias[col];
                if (RELU) v = v > 0.f ? v : 0.f;
                if (SCALEQ && col < 1024) v *= Q_SCALE;
                if (OUT_F32)
                    outf[(size_t)row * N + col] = v;
                else
                    outh[(size_t)row * N + col] = f2bfraw(v);
            }
        }
    }
}

// ---------------- flash attention, S^T form, v3 (r3-exact, session-best) ----
// grid (SEQ/128, NH, BATCH); 8 waves x 512 threads; wave owns 16 q rows.
//  - P never touches LDS: PV's k-axis permuted per 32-slice (pi bijective),
//    V stored pre-permuted so PV B-frag = lane-local packed exp() output.
//  - K double-buffered via global_load_lds with pre-swizzled source.
//  - LDS = 2*16384 (K dbuf) + 16384 (V) = 49152 B; 16 waves/CU.
__global__ __launch_bounds__(512, 4) void attn_kernel(const u16* __restrict__ qkv,
                                                      const u16* __restrict__ vt,
                                                      u16* __restrict__ O) {
    __shared__ __attribute__((aligned(16))) u16 Ks[2][128 * 64]; // [k=128][dk=64], swz
    __shared__ __attribute__((aligned(16))) u16 Vs[64 * 128];    // [dv=64][k-permuted], swz

    const int tid = threadIdx.x;
    const int lane = tid & 63, wid = tid >> 6;
    const int quad = lane >> 4, l16 = lane & 15;
    const int sw = l16 & 7;  // row-swizzle key for all l16-row reads
    const int b = blockIdx.z, h = blockIdx.y;
    const int q0 = blockIdx.x * 128 + wid * 16;

    // Q fragments (B-operand: n=q=l16, k=quad*8+j); Q pre-scaled by Q_SCALE
    const size_t qrow = (size_t)(b * SEQ + q0 + l16) * NQKV + h * DK;
    const bf16x8 qf0 = *(const bf16x8*)&qkv[qrow + quad * 8];
    const bf16x8 qf1 = *(const bf16x8*)&qkv[qrow + 32 + quad * 8];

    const u16* Kbase = qkv + (size_t)(b * SEQ) * NQKV + D_MODEL + h * DK;
    const u16* Vbase = vt + (size_t)((b * NH + h) * DK) * SEQ;

    f32x4 oacc[4];
#pragma unroll
    for (int d = 0; d < 4; d++) oacc[d] = (f32x4){0.f, 0.f, 0.f, 0.f};
    float lr = 0.f;
    const f32x4 Z = {0.f, 0.f, 0.f, 0.f};

    // K tile stage: direct-to-LDS, source pre-swizzled (chunk ^ row&7)
    auto stage_k = [&](int kt2, int buf) {
#pragma unroll
        for (int p = 0; p < 2; p++) {
            int seg = p * 8 + wid;                   // 16 segments of 8 rows
            int row = seg * 8 + (lane >> 3);
            int chunk = (lane & 7) ^ (lane >> 3);    // row&7 == lane>>3
            gload_lds16(&Kbase[(size_t)(kt2 + row) * NQKV + chunk * 8],
                        &Ks[buf][seg * 512]);
        }
    };
    // V tile load to regs (reg-staged: permuted LDS write can't use gload_lds)
    bf16x8 vreg[2];
    auto load_v = [&](int kt2) {
#pragma unroll
        for (int p = 0; p < 2; p++) {
            int s = p * 512 + tid;
            vreg[p] = *(const bf16x8*)&Vbase[(size_t)(s >> 4) * SEQ + kt2 + (s & 15) * 8];
        }
    };
    stage_k(0, 0);
    load_v(0);

    for (int t = 0; t < SEQ / 128; t++) {
        const int kt = t * 128;
        // ---- write V(t) regs -> Vs, k-permuted + swizzled -------------------
#pragma unroll
        for (int p = 0; p < 2; p++) {
            int s = p * 512 + tid;
            int vr = s >> 4, vc = s & 15;
            int chunkA = (vc >> 2) * 4 + (vc & 1) * 2;
            int rem = ((vc >> 1) & 1) * 4;
            u32x4 kv = __builtin_bit_cast(u32x4, vreg[p]);
            *(u32x2*)&Vs[vr * 128 + ((chunkA ^ (vr & 7)) * 8) + rem] =
                (u32x2){kv.x, kv.y};
            *(u32x2*)&Vs[vr * 128 + (((chunkA + 1) ^ (vr & 7)) * 8) + rem] =
                (u32x2){kv.z, kv.w};
        }
        __syncthreads();  // K(t) landed (vmcnt drained), Vs visible to all waves

        // issue next tile's K-to-LDS + V-to-regs; drained at barrier2
        if (t + 1 < SEQ / 128) {
            stage_k(kt + 128, (t + 1) & 1);
            load_v(kt + 128);
        }

        const u16* kb = Ks[t & 1];

        // ---- S^T = K·Q^T : sacc[nt], k=nt*16+quad*4+r, q=l16 ----
        f32x4 sacc[8];
        __builtin_amdgcn_s_setprio(1);
#pragma unroll
        for (int nt = 0; nt < 8; nt++) {
            const u16* krow = &kb[(nt * 16 + l16) * 64];
            bf16x8 kf0 = *(const bf16x8*)&krow[(quad ^ sw) * 8];
            bf16x8 kf1 = *(const bf16x8*)&krow[((4 + quad) ^ sw) * 8];
            f32x4 s0 = __builtin_amdgcn_mfma_f32_16x16x32_bf16(kf0, qf0, Z, 0, 0, 0);
            sacc[nt] = __builtin_amdgcn_mfma_f32_16x16x32_bf16(kf1, qf1, s0, 0, 0, 0);
        }
        __builtin_amdgcn_s_setprio(0);

        // ---- softmax fully in-register: exp2, per-lane sum, pack bf16 ----
        u32 wreg[8][2];
#pragma unroll
        for (int nt = 0; nt < 8; nt++) {
            float p0 = __builtin_amdgcn_exp2f(sacc[nt][0]);
            float p1 = __builtin_amdgcn_exp2f(sacc[nt][1]);
            float p2 = __builtin_amdgcn_exp2f(sacc[nt][2]);
            float p3 = __builtin_amdgcn_exp2f(sacc[nt][3]);
            lr += (p0 + p1) + (p2 + p3);
            wreg[nt][0] = pack_bf2(p0, p1);
            wreg[nt][1] = pack_bf2(p2, p3);
        }

        // ---- O^T += V^T·P^T over permuted k: B-frag is lane-local ----
        __builtin_amdgcn_s_setprio(1);
#pragma unroll
        for (int ks = 0; ks < 4; ks++) {
            u32x4 pw = (u32x4){wreg[2 * ks][0], wreg[2 * ks][1],
                               wreg[2 * ks + 1][0], wreg[2 * ks + 1][1]};
            bf16x8 pf = __builtin_bit_cast(bf16x8, pw);
#pragma unroll
            for (int d = 0; d < 4; d++) {
                bf16x8 vf = *(const bf16x8*)&Vs[(d * 16 + l16) * 128 +
                                                (((ks * 4 + quad) ^ sw) * 8)];
                oacc[d] = __builtin_amdgcn_mfma_f32_16x16x32_bf16(vf, pf, oacc[d], 0, 0, 0);
            }
        }
        __builtin_amdgcn_s_setprio(0);
        __syncthreads();  // all waves done with Ks[t&1]/Vs before restage
    }

    // lane's lr covers its quad's 32 k's per tile; reduce across quads
    lr += __shfl_xor(lr, 16, 64);
    lr += __shfl_xor(lr, 32, 64);
    float iv = 1.f / lr;

    // O^T C-layout: col=q=l16, row=dv=d*16+quad*4+r -> b64 stores
    size_t row = (size_t)(b * SEQ + q0 + l16);
#pragma unroll
    for (int d = 0; d < 4; d++) {
        float o0 = oacc[d][0] * iv, o1 = oacc[d][1] * iv;
        float o2 = oacc[d][2] * iv, o3 = oacc[d][3] * iv;
        u32x2 w;
        w.x = ((u32)f2bfraw(o1) << 16) | f2bfraw(o0);
        w.y = ((u32)f2bfraw(o3) << 16) | f2bfraw(o2);
        *(u32x2*)&O[row * D_MODEL + h * DK + d * 16 + quad * 4] = w;
    }
}

// ---------------- LayerNorm(base + sum of P bf16 partial slices) ------------
// Partials layout: slice z at parts + z*BL*D_MODEL (u16 bf16). Summed in f32.
template <int P>
__global__ __launch_bounds__(256) void lnp_kernel(const float* __restrict__ base,
                                                  const u16* __restrict__ parts,
                                                  const float* __restrict__ g,
                                                  const float* __restrict__ be,
                                                  u16* __restrict__ out_bf,
                                                  float* __restrict__ out_f) {
    int row = blockIdx.x;
    int tid = threadIdx.x;
    int c = tid * 4;
    const float* pb = base + (size_t)row * D_MODEL;
    f32x4 bv = *(const f32x4*)&pb[c];
    float v[4] = {bv[0], bv[1], bv[2], bv[3]};
    size_t off = (size_t)row * D_MODEL + c;
#pragma unroll
    for (int z = 0; z < P; z++) {
        u32x2 pw = *(const u32x2*)&parts[(size_t)z * BL * D_MODEL + off];
        v[0] += bfraw2f((u16)(pw.x & 0xffffu));
        v[1] += bfraw2f((u16)(pw.x >> 16));
        v[2] += bfraw2f((u16)(pw.y & 0xffffu));
        v[3] += bfraw2f((u16)(pw.y >> 16));
    }
    float s = 0.f, ss = 0.f;
#pragma unroll
    for (int i = 0; i < 4; i++) {
        s += v[i];
        ss += v[i] * v[i];
    }
#pragma unroll
    for (int off2 = 32; off2; off2 >>= 1) {
        s += __shfl_down(s, off2, 64);
        ss += __shfl_down(ss, off2, 64);
    }
    __shared__ float red[8];
    int wid = tid >> 6, lane = tid & 63;
    if (lane == 0) { red[wid] = s; red[4 + wid] = ss; }
    __syncthreads();
    if (tid == 0) {
        red[0] = red[0] + red[1] + red[2] + red[3];
        red[4] = red[4] + red[5] + red[6] + red[7];
    }
    __syncthreads();
    float mu = red[0] * (1.f / D_MODEL);
    float var = red[4] * (1.f / D_MODEL) - mu * mu;
    float rs = rsqrtf(var + 1e-5f);
#pragma unroll
    for (int i = 0; i < 4; i++) {
        float o = (v[i] - mu) * rs * g[c + i] + be[c + i];
        if (out_f) out_f[(size_t)row * D_MODEL + c + i] = o;
        if (out_bf) out_bf[(size_t)row * D_MODEL + c + i] = f2bfraw(o);
    }
}

// ---------------- launch ----------------
extern "C" void kernel_launch(void* const* d_in, const int* in_sizes, int n_in,
                              void* d_out, int out_size, void* d_ws, size_t ws_size,
                              hipStream_t stream) {
    const float* x   = (const float*)d_in[0];
    const float* Wq  = (const float*)d_in[1];
    const float* bq  = (const float*)d_in[2];
    const float* Wk  = (const float*)d_in[3];
    const float* bk  = (const float*)d_in[4];
    const float* Wv  = (const float*)d_in[5];
    const float* bv  = (const float*)d_in[6];
    const float* Wo  = (const float*)d_in[7];
    const float* g1  = (const float*)d_in[8];
    const float* be1 = (const float*)d_in[9];
    const float* W1  = (const float*)d_in[10];
    const float* b1  = (const float*)d_in[11];
    const float* W2  = (const float*)d_in[12];
    const float* g2  = (const float*)d_in[13];
    const float* be2 = (const float*)d_in[14];

    char* w = (char*)d_ws;
    auto alloc = [&](size_t bytes) {
        char* p = w;
        w += (bytes + 255) & ~(size_t)255;
        return p;
    };
    u16* wqkv_t = (u16*)alloc((size_t)NQKV * D_MODEL * 2);
    u16* wo_t   = (u16*)alloc((size_t)D_MODEL * D_MODEL * 2);
    u16* w1_t   = (u16*)alloc((size_t)DFF * D_MODEL * 2);
    u16* w2_t   = (u16*)alloc((size_t)D_MODEL * DFF * 2);
    float* bqkv = (float*)alloc((size_t)NQKV * 4);
    u16* x_bf   = (u16*)alloc((size_t)BL * D_MODEL * 2);
    u16* qkvbuf = (u16*)alloc((size_t)BL * NQKV * 2);
    u16* vtbuf  = (u16*)alloc((size_t)BATCH * NH * DK * SEQ * 2);
    u16* obuf   = (u16*)alloc((size_t)BL * D_MODEL * 2);
    u16* mha_pb = (u16*)alloc((size_t)4 * BL * D_MODEL * 2);  // split-K4 bf16 partials
    u16* h1_bf  = (u16*)alloc((size_t)BL * D_MODEL * 2);
    float* h1_f = (float*)alloc((size_t)BL * D_MODEL * 4);
    u16* ffa    = (u16*)alloc((size_t)BL * DFF * 2);
    u16* ffb_pb = (u16*)alloc((size_t)4 * BL * D_MODEL * 2);  // split-K4 bf16 partials

    // merged prep: all weight transposes + bias concat + x cast (1 launch)
    prep_weights<<<dim3(1024, 1, 7), 256, 0, stream>>>(
        Wq, Wk, Wv, Wo, W1, W2, bq, bk, bv, x,
        wqkv_t, wo_t, w1_t, w2_t, bqkv, x_bf);

    // QKV = x @ Wqkv^T + bias -> Q,K bf16 into qkvbuf; V transposed into vtbuf
    gemm_bt<0, 0, 1, 1, 1, 1><<<dim3(32, 24), 256, 0, stream>>>(
        x_bf, wqkv_t, bqkv, qkvbuf, vtbuf, BL, NQKV, D_MODEL);
    // flash attention -> O bf16 [4096][1024]
    attn_kernel<<<dim3(16, 16, 2), 512, 0, stream>>>(qkvbuf, vtbuf, obuf);
    // mha partials = O @ Wo (split-K=4, bf16 partials) -> 4 blocks/CU
    gemm_bt<0, 0, 0, 4, 0, 0><<<dim3(32, 8, 4), 256, 0, stream>>>(
        obuf, wo_t, nullptr, mha_pb, nullptr, BL, D_MODEL, D_MODEL);
    // h1 = LN(x + sum of 4 mha partials)
    lnp_kernel<4><<<dim3(BL), 256, 0, stream>>>(x, mha_pb, g1, be1, h1_bf, h1_f);
    // ffa = relu(h1 @ W1 + b1) -> bf16 [4096][4096]
    gemm_bt<0, 1, 1, 1, 0, 0><<<dim3(32, 32), 256, 0, stream>>>(
        h1_bf, w1_t, b1, ffa, nullptr, BL, DFF, D_MODEL);
    // ffb partials = ffa @ W2 (split-K=4, bf16 partials) -> 4 blocks/CU
    gemm_bt<0, 0, 0, 4, 0, 0><<<dim3(32, 8, 4), 256, 0, stream>>>(
        ffa, w2_t, nullptr, ffb_pb, nullptr, BL, D_MODEL, DFF);
    // out = LN(h1 + sum of 4 ffb partials)
    lnp_kernel<4><<<dim3(BL), 256, 0, stream>>>(h1_f, ffb_pb, g2, be2,
                                                nullptr, (float*)d_out);
}

// Round 12
// 340.525 us; speedup vs baseline: 1.0780x; 1.0449x over previous
//
#include <hip/hip_runtime.h>

typedef unsigned short u16;
typedef unsigned int u32;
typedef short bf16x8 __attribute__((ext_vector_type(8)));
typedef float f32x4 __attribute__((ext_vector_type(4)));
typedef unsigned int u32x2 __attribute__((ext_vector_type(2)));
typedef unsigned int u32x4 __attribute__((ext_vector_type(4)));

#define D_MODEL 1024
#define NH 16
#define DK 64
#define DFF 4096
#define BATCH 2
#define SEQ 2048
#define BL (BATCH*SEQ)
#define NQKV 3072
// fold (1/sqrt(64)) * log2(e) into Q so softmax is raw exp2 (v_exp_f32)
#define Q_SCALE 0.18033688011f

__device__ __forceinline__ float bfraw2f(u16 u) {
    union { u32 i; float f; } c; c.i = ((u32)u) << 16; return c.f;
}
__device__ __forceinline__ u16 f2bfraw(float f) {
    union { float f; u32 i; } c; c.f = f;
    u32 i = c.i;
    u32 lsb = (i >> 16) & 1u;
    i += 0x7fffu + lsb;
    return (u16)(i >> 16);
}
__device__ __forceinline__ u32 fasu(float f) {
    union { float f; u32 i; } c; c.f = f; return c.i;
}
// pack two f32 -> (bf16(hi)<<16)|bf16(lo), round-to-nearest via +0x8000
__device__ __forceinline__ u32 pack_bf2(float lo, float hi) {
    return __builtin_amdgcn_perm(fasu(hi) + 0x8000u, fasu(lo) + 0x8000u,
                                 0x07060302u);
}
// single-instruction pack: dst.lo=bf16(lo), dst.hi=bf16(hi) (RNE). No builtin
// on gfx950 (T12/m240) -> inline asm. Replaces pack_bf2's 3 VALU with 1.
__device__ __forceinline__ u32 cvtpk_bf2(float lo, float hi) {
    u32 r;
    asm("v_cvt_pk_bf16_f32 %0, %1, %2" : "=v"(r) : "v"(lo), "v"(hi));
    return r;
}
// async global->LDS 16B per lane (dest = wave-uniform base + lane*16)
__device__ __forceinline__ void gload_lds16(const u16* g, u16* l) {
    __builtin_amdgcn_global_load_lds(
        (const __attribute__((address_space(1))) void*)g,
        (__attribute__((address_space(3))) void*)l, 16, 0, 0);
}

// ---------------- merged prep: weight transposes + bias concat + x cast -----
// grid (1024, 1, 7), 256 thr.
// z=0..2: Wq/Wk/Wv per-head transpose into fused [3072][1024] B^T layout
//         (z=0 blocks 256..267 also do the bias concat).
// z=3: Wo (1024x1024). z=4: W1 (1024x4096). z=5: W2 (4096x1024).
// z=6: x f32 -> bf16 cast, 4 chunks per block.
__global__ __launch_bounds__(256) void prep_weights(
    const float* __restrict__ Wq, const float* __restrict__ Wk,
    const float* __restrict__ Wv, const float* __restrict__ Wo,
    const float* __restrict__ W1, const float* __restrict__ W2,
    const float* __restrict__ bq, const float* __restrict__ bk,
    const float* __restrict__ bv, const float* __restrict__ x,
    u16* __restrict__ wqkv_t, u16* __restrict__ wo_t,
    u16* __restrict__ w1_t, u16* __restrict__ w2_t,
    float* __restrict__ bqkv, u16* __restrict__ x_bf) {
    __shared__ u16 t[64][65];
    const int z = blockIdx.z, bx = blockIdx.x;
    const int col = threadIdx.x & 63, rr = threadIdx.x >> 6;

    if (z == 6) {
        // cast x: 4096*1024 f32 -> bf16; 1024 blocks x 4 chunks x 1024 elems
#pragma unroll
        for (int j = 0; j < 4; j++) {
            int i = (((j << 10) + bx) * 256 + threadIdx.x) * 4;
            f32x4 v = *(const f32x4*)&x[i];
#pragma unroll
            for (int e = 0; e < 4; e++) x_bf[i + e] = f2bfraw(v[e]);
        }
        return;
    }

    if (z < 3) {
        if (bx >= 256) {
            if (z == 0 && bx < 268) {
                int i = (bx - 256) * 256 + threadIdx.x;
                bqkv[i] = (i < 1024) ? bq[i]
                        : (i < 2048) ? bk[i - 1024] : bv[i - 2048];
            }
            return;
        }
        const int d0 = (bx & 15) * 64, h = bx >> 4;
        const float* W = (z == 0) ? Wq : (z == 1) ? Wk : Wv;
        const float* src = W + (size_t)h * D_MODEL * DK;
        for (int i = rr; i < 64; i += 4)
            t[i][col] = f2bfraw(src[(size_t)(d0 + i) * DK + col]);
        __syncthreads();
        u16* dst = wqkv_t + (size_t)(z * 1024 + h * 64) * D_MODEL;
        for (int i = rr; i < 64; i += 4)
            dst[(size_t)i * D_MODEL + d0 + col] = t[col][i];
        return;
    }

    const float* in; u16* out; int R, C;
    if (z == 3)      { in = Wo; out = wo_t; R = 1024; C = 1024; }
    else if (z == 4) { in = W1; out = w1_t; R = 1024; C = 4096; }
    else             { in = W2; out = w2_t; R = 4096; C = 1024; }
    const int ctiles = C >> 6;
    const int rt = bx / ctiles, ct = bx % ctiles;
    if (rt >= (R >> 6)) return;
    const int c0 = ct * 64, r0 = rt * 64;
    for (int i = rr; i < 64; i += 4)
        t[i][col] = f2bfraw(in[(size_t)(r0 + i) * C + c0 + col]);
    __syncthreads();
    for (int i = rr; i < 64; i += 4)
        out[(size_t)(c0 + i) * R + r0 + col] = t[col][i];
}

// ---------------- GEMM: C[M][N] = A[M][K] @ Bt[N][K]^T ----------------
// m97 structure (r2-exact, session-best): 128x128 tile, BK=64, unpadded LDS,
// global_load_lds width 16, NO XCD swizzle (r7: wrecks A-panel L2 reuse).
// bf16 output path carries the split-K z-offset -> split-K partials can be
// bf16 (halves partial traffic; enables split-K=4 at neutral bytes).
// VSTORE: blocks with n0>=2048 (V section of QKV) store transposed into vtout
//         [b][h][dv][l] as 8B packed bf16.

template <int OUT_F32, int RELU, int HASBIAS, int SPLITK, int SCALEQ, int VSTORE>
__global__ __launch_bounds__(256, 4) void gemm_bt(const u16* __restrict__ A,
                                                  const u16* __restrict__ Bt,
                                                  const float* __restrict__ bias,
                                                  void* __restrict__ Cout,
                                                  u16* __restrict__ vtout,
                                                  int M, int N, int K) {
    __shared__ __attribute__((aligned(16))) u16 As[128 * 64];
    __shared__ __attribute__((aligned(16))) u16 Bs[128 * 64];
    const int tid = threadIdx.x;
    const int lane = tid & 63, wid = tid >> 6;
    const int quad = lane >> 4, l16 = lane & 15;
    const int m0 = blockIdx.x * 128, n0 = blockIdx.y * 128;
    const int z = (SPLITK > 1) ? blockIdx.z : 0;
    const int Klen = K / SPLITK;
    const int kend = (z + 1) * Klen;
    const int wm = (wid >> 1) * 64, wn = (wid & 1) * 64;

    f32x4 acc[4][4];
#pragma unroll
    for (int i = 0; i < 4; i++)
#pragma unroll
        for (int j = 0; j < 4; j++) acc[i][j] = (f32x4){0.f, 0.f, 0.f, 0.f};

    const int srow = lane >> 3, scol = (lane & 7) * 8;

    for (int kb = z * Klen; kb < kend; kb += 64) {
#pragma unroll
        for (int p = 0; p < 4; p++) {
            int c = wid * 4 + p;
            int row = c * 8 + srow;
            gload_lds16(&A[(size_t)(m0 + row) * K + kb + scol], &As[c * 512]);
            gload_lds16(&Bt[(size_t)(n0 + row) * K + kb + scol], &Bs[c * 512]);
        }
        __syncthreads();
#pragma unroll
        for (int kh = 0; kh < 2; kh++) {
            bf16x8 af[4], bf[4];
#pragma unroll
            for (int t = 0; t < 4; t++) {
                af[t] = *(const bf16x8*)&As[(wm + t * 16 + l16) * 64 + kh * 32 + quad * 8];
                bf[t] = *(const bf16x8*)&Bs[(wn + t * 16 + l16) * 64 + kh * 32 + quad * 8];
            }
#pragma unroll
            for (int i = 0; i < 4; i++)
#pragma unroll
                for (int j = 0; j < 4; j++)
                    acc[i][j] = __builtin_amdgcn_mfma_f32_16x16x32_bf16(
                        af[i], bf[j], acc[i][j], 0, 0, 0);
        }
        __syncthreads();
    }

    if (VSTORE && n0 >= 2048) {
        // V section -> vtout[b][dv][l], dv = col-2048, 4 consecutive l per store
#pragma unroll
        for (int i = 0; i < 4; i++) {
            int row0 = m0 + wm + i * 16 + quad * 4;
            int bb = row0 >> 11, l = row0 & 2047;
#pragma unroll
            for (int j = 0; j < 4; j++) {
                int col = n0 + wn + j * 16 + l16;
                float bv = HASBIAS ? bias[col] : 0.f;
                int dv = col - 2048;
                u32x2 w;
                w.x = pack_bf2(acc[i][j][0] + bv, acc[i][j][1] + bv);
                w.y = pack_bf2(acc[i][j][2] + bv, acc[i][j][3] + bv);
                *(u32x2*)&vtout[((size_t)(bb * 1024 + dv)) * 2048 + l] = w;
            }
        }
        return;
    }

    float* outf = (float*)Cout + (size_t)z * M * N;
    u16* outh = (u16*)Cout + (size_t)z * M * N;
#pragma unroll
    for (int i = 0; i < 4; i++) {
#pragma unroll
        for (int j = 0; j < 4; j++) {
#pragma unroll
            for (int r = 0; r < 4; r++) {
                int row = m0 + wm + i * 16 + quad * 4 + r;
                int col = n0 + wn + j * 16 + l16;
                float v = acc[i][j][r];
                if (HASBIAS) v += bias[col];
                if (RELU) v = v > 0.f ? v : 0.f;
                if (SCALEQ && col < 1024) v *= Q_SCALE;
                if (OUT_F32)
                    outf[(size_t)row * N + col] = v;
                else
                    outh[(size_t)row * N + col] = f2bfraw(v);
            }
        }
    }
}

// ---------------- flash attention, S^T form, v3 + cvt_pk softmax ------------
// grid (SEQ/128, NH, BATCH); 8 waves x 512 threads; wave owns 16 q rows.
//  - P never touches LDS: PV's k-axis permuted per 32-slice (pi bijective),
//    V stored pre-permuted so PV B-frag = lane-local packed exp() output.
//  - K double-buffered via global_load_lds with pre-swizzled source.
//  - r12: softmax pack via v_cvt_pk_bf16_f32 (1 VALU vs pack_bf2's 3).
//  - LDS = 2*16384 (K dbuf) + 16384 (V) = 49152 B; 16 waves/CU.
__global__ __launch_bounds__(512, 4) void attn_kernel(const u16* __restrict__ qkv,
                                                      const u16* __restrict__ vt,
                                                      u16* __restrict__ O) {
    __shared__ __attribute__((aligned(16))) u16 Ks[2][128 * 64]; // [k=128][dk=64], swz
    __shared__ __attribute__((aligned(16))) u16 Vs[64 * 128];    // [dv=64][k-permuted], swz

    const int tid = threadIdx.x;
    const int lane = tid & 63, wid = tid >> 6;
    const int quad = lane >> 4, l16 = lane & 15;
    const int sw = l16 & 7;  // row-swizzle key for all l16-row reads
    const int b = blockIdx.z, h = blockIdx.y;
    const int q0 = blockIdx.x * 128 + wid * 16;

    // Q fragments (B-operand: n=q=l16, k=quad*8+j); Q pre-scaled by Q_SCALE
    const size_t qrow = (size_t)(b * SEQ + q0 + l16) * NQKV + h * DK;
    const bf16x8 qf0 = *(const bf16x8*)&qkv[qrow + quad * 8];
    const bf16x8 qf1 = *(const bf16x8*)&qkv[qrow + 32 + quad * 8];

    const u16* Kbase = qkv + (size_t)(b * SEQ) * NQKV + D_MODEL + h * DK;
    const u16* Vbase = vt + (size_t)((b * NH + h) * DK) * SEQ;

    f32x4 oacc[4];
#pragma unroll
    for (int d = 0; d < 4; d++) oacc[d] = (f32x4){0.f, 0.f, 0.f, 0.f};
    float lr = 0.f;
    const f32x4 Z = {0.f, 0.f, 0.f, 0.f};

    // K tile stage: direct-to-LDS, source pre-swizzled (chunk ^ row&7)
    auto stage_k = [&](int kt2, int buf) {
#pragma unroll
        for (int p = 0; p < 2; p++) {
            int seg = p * 8 + wid;                   // 16 segments of 8 rows
            int row = seg * 8 + (lane >> 3);
            int chunk = (lane & 7) ^ (lane >> 3);    // row&7 == lane>>3
            gload_lds16(&Kbase[(size_t)(kt2 + row) * NQKV + chunk * 8],
                        &Ks[buf][seg * 512]);
        }
    };
    // V tile load to regs (reg-staged: permuted LDS write can't use gload_lds)
    bf16x8 vreg[2];
    auto load_v = [&](int kt2) {
#pragma unroll
        for (int p = 0; p < 2; p++) {
            int s = p * 512 + tid;
            vreg[p] = *(const bf16x8*)&Vbase[(size_t)(s >> 4) * SEQ + kt2 + (s & 15) * 8];
        }
    };
    stage_k(0, 0);
    load_v(0);

    for (int t = 0; t < SEQ / 128; t++) {
        const int kt = t * 128;
        // ---- write V(t) regs -> Vs, k-permuted + swizzled -------------------
#pragma unroll
        for (int p = 0; p < 2; p++) {
            int s = p * 512 + tid;
            int vr = s >> 4, vc = s & 15;
            int chunkA = (vc >> 2) * 4 + (vc & 1) * 2;
            int rem = ((vc >> 1) & 1) * 4;
            u32x4 kv = __builtin_bit_cast(u32x4, vreg[p]);
            *(u32x2*)&Vs[vr * 128 + ((chunkA ^ (vr & 7)) * 8) + rem] =
                (u32x2){kv.x, kv.y};
            *(u32x2*)&Vs[vr * 128 + (((chunkA + 1) ^ (vr & 7)) * 8) + rem] =
                (u32x2){kv.z, kv.w};
        }
        __syncthreads();  // K(t) landed (vmcnt drained), Vs visible to all waves

        // issue next tile's K-to-LDS + V-to-regs; drained at barrier2
        if (t + 1 < SEQ / 128) {
            stage_k(kt + 128, (t + 1) & 1);
            load_v(kt + 128);
        }

        const u16* kb = Ks[t & 1];

        // ---- S^T = K·Q^T : sacc[nt], k=nt*16+quad*4+r, q=l16 ----
        f32x4 sacc[8];
        __builtin_amdgcn_s_setprio(1);
#pragma unroll
        for (int nt = 0; nt < 8; nt++) {
            const u16* krow = &kb[(nt * 16 + l16) * 64];
            bf16x8 kf0 = *(const bf16x8*)&krow[(quad ^ sw) * 8];
            bf16x8 kf1 = *(const bf16x8*)&krow[((4 + quad) ^ sw) * 8];
            f32x4 s0 = __builtin_amdgcn_mfma_f32_16x16x32_bf16(kf0, qf0, Z, 0, 0, 0);
            sacc[nt] = __builtin_amdgcn_mfma_f32_16x16x32_bf16(kf1, qf1, s0, 0, 0, 0);
        }
        __builtin_amdgcn_s_setprio(0);

        // ---- softmax fully in-register: exp2, per-lane sum, cvt_pk bf16 ----
        u32 wreg[8][2];
#pragma unroll
        for (int nt = 0; nt < 8; nt++) {
            float p0 = __builtin_amdgcn_exp2f(sacc[nt][0]);
            float p1 = __builtin_amdgcn_exp2f(sacc[nt][1]);
            float p2 = __builtin_amdgcn_exp2f(sacc[nt][2]);
            float p3 = __builtin_amdgcn_exp2f(sacc[nt][3]);
            lr += (p0 + p1) + (p2 + p3);
            wreg[nt][0] = cvtpk_bf2(p0, p1);
            wreg[nt][1] = cvtpk_bf2(p2, p3);
        }

        // ---- O^T += V^T·P^T over permuted k: B-frag is lane-local ----
        __builtin_amdgcn_s_setprio(1);
#pragma unroll
        for (int ks = 0; ks < 4; ks++) {
            u32x4 pw = (u32x4){wreg[2 * ks][0], wreg[2 * ks][1],
                               wreg[2 * ks + 1][0], wreg[2 * ks + 1][1]};
            bf16x8 pf = __builtin_bit_cast(bf16x8, pw);
#pragma unroll
            for (int d = 0; d < 4; d++) {
                bf16x8 vf = *(const bf16x8*)&Vs[(d * 16 + l16) * 128 +
                                                (((ks * 4 + quad) ^ sw) * 8)];
                oacc[d] = __builtin_amdgcn_mfma_f32_16x16x32_bf16(vf, pf, oacc[d], 0, 0, 0);
            }
        }
        __builtin_amdgcn_s_setprio(0);
        __syncthreads();  // all waves done with Ks[t&1]/Vs before restage
    }

    // lane's lr covers its quad's 32 k's per tile; reduce across quads
    lr += __shfl_xor(lr, 16, 64);
    lr += __shfl_xor(lr, 32, 64);
    float iv = 1.f / lr;

    // O^T C-layout: col=q=l16, row=dv=d*16+quad*4+r -> b64 stores
    size_t row = (size_t)(b * SEQ + q0 + l16);
#pragma unroll
    for (int d = 0; d < 4; d++) {
        float o0 = oacc[d][0] * iv, o1 = oacc[d][1] * iv;
        float o2 = oacc[d][2] * iv, o3 = oacc[d][3] * iv;
        u32x2 w;
        w.x = ((u32)f2bfraw(o1) << 16) | f2bfraw(o0);
        w.y = ((u32)f2bfraw(o3) << 16) | f2bfraw(o2);
        *(u32x2*)&O[row * D_MODEL + h * DK + d * 16 + quad * 4] = w;
    }
}

// ---------------- LayerNorm(base + sum of P bf16 partial slices) ------------
// Partials layout: slice z at parts + z*BL*D_MODEL (u16 bf16). Summed in f32.
// BASEBF: base stream is bf16 (u16) instead of f32 (saves the f32 h1 stream).
template <int P, int BASEBF>
__global__ __launch_bounds__(256) void lnp_kernel(const void* __restrict__ base,
                                                  const u16* __restrict__ parts,
                                                  const float* __restrict__ g,
                                                  const float* __restrict__ be,
                                                  u16* __restrict__ out_bf,
                                                  float* __restrict__ out_f) {
    int row = blockIdx.x;
    int tid = threadIdx.x;
    int c = tid * 4;
    size_t off = (size_t)row * D_MODEL + c;
    float v[4];
    if (BASEBF) {
        u32x2 bw = *(const u32x2*)&((const u16*)base)[off];
        v[0] = bfraw2f((u16)(bw.x & 0xffffu));
        v[1] = bfraw2f((u16)(bw.x >> 16));
        v[2] = bfraw2f((u16)(bw.y & 0xffffu));
        v[3] = bfraw2f((u16)(bw.y >> 16));
    } else {
        f32x4 bv = *(const f32x4*)&((const float*)base)[off];
        v[0] = bv[0]; v[1] = bv[1]; v[2] = bv[2]; v[3] = bv[3];
    }
#pragma unroll
    for (int z = 0; z < P; z++) {
        u32x2 pw = *(const u32x2*)&parts[(size_t)z * BL * D_MODEL + off];
        v[0] += bfraw2f((u16)(pw.x & 0xffffu));
        v[1] += bfraw2f((u16)(pw.x >> 16));
        v[2] += bfraw2f((u16)(pw.y & 0xffffu));
        v[3] += bfraw2f((u16)(pw.y >> 16));
    }
    float s = 0.f, ss = 0.f;
#pragma unroll
    for (int i = 0; i < 4; i++) {
        s += v[i];
        ss += v[i] * v[i];
    }
#pragma unroll
    for (int off2 = 32; off2; off2 >>= 1) {
        s += __shfl_down(s, off2, 64);
        ss += __shfl_down(ss, off2, 64);
    }
    __shared__ float red[8];
    int wid = tid >> 6, lane = tid & 63;
    if (lane == 0) { red[wid] = s; red[4 + wid] = ss; }
    __syncthreads();
    if (tid == 0) {
        red[0] = red[0] + red[1] + red[2] + red[3];
        red[4] = red[4] + red[5] + red[6] + red[7];
    }
    __syncthreads();
    float mu = red[0] * (1.f / D_MODEL);
    float var = red[4] * (1.f / D_MODEL) - mu * mu;
    float rs = rsqrtf(var + 1e-5f);
#pragma unroll
    for (int i = 0; i < 4; i++) {
        float o = (v[i] - mu) * rs * g[c + i] + be[c + i];
        if (out_f) out_f[(size_t)row * D_MODEL + c + i] = o;
        if (out_bf) out_bf[(size_t)row * D_MODEL + c + i] = f2bfraw(o);
    }
}

// ---------------- launch ----------------
extern "C" void kernel_launch(void* const* d_in, const int* in_sizes, int n_in,
                              void* d_out, int out_size, void* d_ws, size_t ws_size,
                              hipStream_t stream) {
    const float* x   = (const float*)d_in[0];
    const float* Wq  = (const float*)d_in[1];
    const float* bq  = (const float*)d_in[2];
    const float* Wk  = (const float*)d_in[3];
    const float* bk  = (const float*)d_in[4];
    const float* Wv  = (const float*)d_in[5];
    const float* bv  = (const float*)d_in[6];
    const float* Wo  = (const float*)d_in[7];
    const float* g1  = (const float*)d_in[8];
    const float* be1 = (const float*)d_in[9];
    const float* W1  = (const float*)d_in[10];
    const float* b1  = (const float*)d_in[11];
    const float* W2  = (const float*)d_in[12];
    const float* g2  = (const float*)d_in[13];
    const float* be2 = (const float*)d_in[14];

    char* w = (char*)d_ws;
    auto alloc = [&](size_t bytes) {
        char* p = w;
        w += (bytes + 255) & ~(size_t)255;
        return p;
    };
    u16* wqkv_t = (u16*)alloc((size_t)NQKV * D_MODEL * 2);
    u16* wo_t   = (u16*)alloc((size_t)D_MODEL * D_MODEL * 2);
    u16* w1_t   = (u16*)alloc((size_t)DFF * D_MODEL * 2);
    u16* w2_t   = (u16*)alloc((size_t)D_MODEL * DFF * 2);
    float* bqkv = (float*)alloc((size_t)NQKV * 4);
    u16* x_bf   = (u16*)alloc((size_t)BL * D_MODEL * 2);
    u16* qkvbuf = (u16*)alloc((size_t)BL * NQKV * 2);
    u16* vtbuf  = (u16*)alloc((size_t)BATCH * NH * DK * SEQ * 2);
    u16* obuf   = (u16*)alloc((size_t)BL * D_MODEL * 2);
    u16* mha_pb = (u16*)alloc((size_t)4 * BL * D_MODEL * 2);  // split-K4 bf16 partials
    u16* h1_bf  = (u16*)alloc((size_t)BL * D_MODEL * 2);
    u16* ffa    = (u16*)alloc((size_t)BL * DFF * 2);
    u16* ffb_pb = (u16*)alloc((size_t)4 * BL * D_MODEL * 2);  // split-K4 bf16 partials

    // merged prep: all weight transposes + bias concat + x cast (1 launch)
    prep_weights<<<dim3(1024, 1, 7), 256, 0, stream>>>(
        Wq, Wk, Wv, Wo, W1, W2, bq, bk, bv, x,
        wqkv_t, wo_t, w1_t, w2_t, bqkv, x_bf);

    // QKV = x @ Wqkv^T + bias -> Q,K bf16 into qkvbuf; V transposed into vtbuf
    gemm_bt<0, 0, 1, 1, 1, 1><<<dim3(32, 24), 256, 0, stream>>>(
        x_bf, wqkv_t, bqkv, qkvbuf, vtbuf, BL, NQKV, D_MODEL);
    // flash attention -> O bf16 [4096][1024]
    attn_kernel<<<dim3(16, 16, 2), 512, 0, stream>>>(qkvbuf, vtbuf, obuf);
    // mha partials = O @ Wo (split-K=4, bf16 partials) -> 4 blocks/CU
    gemm_bt<0, 0, 0, 4, 0, 0><<<dim3(32, 8, 4), 256, 0, stream>>>(
        obuf, wo_t, nullptr, mha_pb, nullptr, BL, D_MODEL, D_MODEL);
    // h1 = LN(x + sum of 4 mha partials) -> bf16 only (no f32 stream)
    lnp_kernel<4, 0><<<dim3(BL), 256, 0, stream>>>(x, mha_pb, g1, be1,
                                                   h1_bf, nullptr);
    // ffa = relu(h1 @ W1 + b1) -> bf16 [4096][4096]
    gemm_bt<0, 1, 1, 1, 0, 0><<<dim3(32, 32), 256, 0, stream>>>(
        h1_bf, w1_t, b1, ffa, nullptr, BL, DFF, D_MODEL);
    // ffb partials = ffa @ W2 (split-K=4, bf16 partials) -> 4 blocks/CU
    gemm_bt<0, 0, 0, 4, 0, 0><<<dim3(32, 8, 4), 256, 0, stream>>>(
        ffa, w2_t, nullptr, ffb_pb, nullptr, BL, D_MODEL, DFF);
    // out = LN(h1_bf + sum of 4 ffb partials)
    lnp_kernel<4, 1><<<dim3(BL), 256, 0, stream>>>(h1_bf, ffb_pb, g2, be2,
                                                   nullptr, (float*)d_out);
}

// Round 13
// 334.462 us; speedup vs baseline: 1.0975x; 1.0181x over previous
//
#include <hip/hip_runtime.h>

typedef unsigned short u16;
typedef unsigned int u32;
typedef short bf16x8 __attribute__((ext_vector_type(8)));
typedef float f32x4 __attribute__((ext_vector_type(4)));
typedef unsigned int u32x2 __attribute__((ext_vector_type(2)));
typedef unsigned int u32x4 __attribute__((ext_vector_type(4)));

#define D_MODEL 1024
#define NH 16
#define DK 64
#define DFF 4096
#define BATCH 2
#define SEQ 2048
#define BL (BATCH*SEQ)
#define NQKV 3072
// fold (1/sqrt(64)) * log2(e) into Q so softmax is raw exp2 (v_exp_f32)
#define Q_SCALE 0.18033688011f

__device__ __forceinline__ float bfraw2f(u16 u) {
    union { u32 i; float f; } c; c.i = ((u32)u) << 16; return c.f;
}
__device__ __forceinline__ u16 f2bfraw(float f) {
    union { float f; u32 i; } c; c.f = f;
    u32 i = c.i;
    u32 lsb = (i >> 16) & 1u;
    i += 0x7fffu + lsb;
    return (u16)(i >> 16);
}
__device__ __forceinline__ u32 fasu(float f) {
    union { float f; u32 i; } c; c.f = f; return c.i;
}
// pack two f32 -> (bf16(hi)<<16)|bf16(lo), round-to-nearest via +0x8000
__device__ __forceinline__ u32 pack_bf2(float lo, float hi) {
    return __builtin_amdgcn_perm(fasu(hi) + 0x8000u, fasu(lo) + 0x8000u,
                                 0x07060302u);
}
// single-instruction pack: dst.lo=bf16(lo), dst.hi=bf16(hi) (RNE). No builtin
// on gfx950 (T12/m240) -> inline asm. Replaces pack_bf2's 3 VALU with 1.
__device__ __forceinline__ u32 cvtpk_bf2(float lo, float hi) {
    u32 r;
    asm("v_cvt_pk_bf16_f32 %0, %1, %2" : "=v"(r) : "v"(lo), "v"(hi));
    return r;
}
// async global->LDS 16B per lane (dest = wave-uniform base + lane*16)
__device__ __forceinline__ void gload_lds16(const u16* g, u16* l) {
    __builtin_amdgcn_global_load_lds(
        (const __attribute__((address_space(1))) void*)g,
        (__attribute__((address_space(3))) void*)l, 16, 0, 0);
}

// ---------------- merged prep: weight transposes + bias concat + x cast -----
// grid (1024, 1, 7), 256 thr.
// z=0..2: Wq/Wk/Wv per-head transpose into fused [3072][1024] B^T layout
//         (z=0 blocks 256..267 also do the bias concat).
// z=3: Wo (1024x1024). z=4: W1 (1024x4096). z=5: W2 (4096x1024).
// z=6: x f32 -> bf16 cast, 4 chunks per block.
__global__ __launch_bounds__(256) void prep_weights(
    const float* __restrict__ Wq, const float* __restrict__ Wk,
    const float* __restrict__ Wv, const float* __restrict__ Wo,
    const float* __restrict__ W1, const float* __restrict__ W2,
    const float* __restrict__ bq, const float* __restrict__ bk,
    const float* __restrict__ bv, const float* __restrict__ x,
    u16* __restrict__ wqkv_t, u16* __restrict__ wo_t,
    u16* __restrict__ w1_t, u16* __restrict__ w2_t,
    float* __restrict__ bqkv, u16* __restrict__ x_bf) {
    __shared__ u16 t[64][65];
    const int z = blockIdx.z, bx = blockIdx.x;
    const int col = threadIdx.x & 63, rr = threadIdx.x >> 6;

    if (z == 6) {
        // cast x: 4096*1024 f32 -> bf16; 1024 blocks x 4 chunks x 1024 elems
#pragma unroll
        for (int j = 0; j < 4; j++) {
            int i = (((j << 10) + bx) * 256 + threadIdx.x) * 4;
            f32x4 v = *(const f32x4*)&x[i];
#pragma unroll
            for (int e = 0; e < 4; e++) x_bf[i + e] = f2bfraw(v[e]);
        }
        return;
    }

    if (z < 3) {
        if (bx >= 256) {
            if (z == 0 && bx < 268) {
                int i = (bx - 256) * 256 + threadIdx.x;
                bqkv[i] = (i < 1024) ? bq[i]
                        : (i < 2048) ? bk[i - 1024] : bv[i - 2048];
            }
            return;
        }
        const int d0 = (bx & 15) * 64, h = bx >> 4;
        const float* W = (z == 0) ? Wq : (z == 1) ? Wk : Wv;
        const float* src = W + (size_t)h * D_MODEL * DK;
        for (int i = rr; i < 64; i += 4)
            t[i][col] = f2bfraw(src[(size_t)(d0 + i) * DK + col]);
        __syncthreads();
        u16* dst = wqkv_t + (size_t)(z * 1024 + h * 64) * D_MODEL;
        for (int i = rr; i < 64; i += 4)
            dst[(size_t)i * D_MODEL + d0 + col] = t[col][i];
        return;
    }

    const float* in; u16* out; int R, C;
    if (z == 3)      { in = Wo; out = wo_t; R = 1024; C = 1024; }
    else if (z == 4) { in = W1; out = w1_t; R = 1024; C = 4096; }
    else             { in = W2; out = w2_t; R = 4096; C = 1024; }
    const int ctiles = C >> 6;
    const int rt = bx / ctiles, ct = bx % ctiles;
    if (rt >= (R >> 6)) return;
    const int c0 = ct * 64, r0 = rt * 64;
    for (int i = rr; i < 64; i += 4)
        t[i][col] = f2bfraw(in[(size_t)(r0 + i) * C + c0 + col]);
    __syncthreads();
    for (int i = rr; i < 64; i += 4)
        out[(size_t)(c0 + i) * R + r0 + col] = t[col][i];
}

// ---------------- GEMM: C[M][N] = A[M][K] @ Bt[N][K]^T ----------------
// m97 structure (r2-exact, session-best): 128x128 tile, BK=64, unpadded LDS,
// global_load_lds width 16, NO XCD swizzle (r7: wrecks A-panel L2 reuse).
// bf16 output path carries the split-K z-offset -> split-K partials can be
// bf16 (halves partial traffic; enables split-K=4 at neutral bytes).
// VSTORE: blocks with n0>=2048 (V section of QKV) store transposed into vtout
//         [b][h][dv][l] as 8B packed bf16.

template <int OUT_F32, int RELU, int HASBIAS, int SPLITK, int SCALEQ, int VSTORE>
__global__ __launch_bounds__(256, 4) void gemm_bt(const u16* __restrict__ A,
                                                  const u16* __restrict__ Bt,
                                                  const float* __restrict__ bias,
                                                  void* __restrict__ Cout,
                                                  u16* __restrict__ vtout,
                                                  int M, int N, int K) {
    __shared__ __attribute__((aligned(16))) u16 As[128 * 64];
    __shared__ __attribute__((aligned(16))) u16 Bs[128 * 64];
    const int tid = threadIdx.x;
    const int lane = tid & 63, wid = tid >> 6;
    const int quad = lane >> 4, l16 = lane & 15;
    const int m0 = blockIdx.x * 128, n0 = blockIdx.y * 128;
    const int z = (SPLITK > 1) ? blockIdx.z : 0;
    const int Klen = K / SPLITK;
    const int kend = (z + 1) * Klen;
    const int wm = (wid >> 1) * 64, wn = (wid & 1) * 64;

    f32x4 acc[4][4];
#pragma unroll
    for (int i = 0; i < 4; i++)
#pragma unroll
        for (int j = 0; j < 4; j++) acc[i][j] = (f32x4){0.f, 0.f, 0.f, 0.f};

    const int srow = lane >> 3, scol = (lane & 7) * 8;

    for (int kb = z * Klen; kb < kend; kb += 64) {
#pragma unroll
        for (int p = 0; p < 4; p++) {
            int c = wid * 4 + p;
            int row = c * 8 + srow;
            gload_lds16(&A[(size_t)(m0 + row) * K + kb + scol], &As[c * 512]);
            gload_lds16(&Bt[(size_t)(n0 + row) * K + kb + scol], &Bs[c * 512]);
        }
        __syncthreads();
#pragma unroll
        for (int kh = 0; kh < 2; kh++) {
            bf16x8 af[4], bf[4];
#pragma unroll
            for (int t = 0; t < 4; t++) {
                af[t] = *(const bf16x8*)&As[(wm + t * 16 + l16) * 64 + kh * 32 + quad * 8];
                bf[t] = *(const bf16x8*)&Bs[(wn + t * 16 + l16) * 64 + kh * 32 + quad * 8];
            }
#pragma unroll
            for (int i = 0; i < 4; i++)
#pragma unroll
                for (int j = 0; j < 4; j++)
                    acc[i][j] = __builtin_amdgcn_mfma_f32_16x16x32_bf16(
                        af[i], bf[j], acc[i][j], 0, 0, 0);
        }
        __syncthreads();
    }

    if (VSTORE && n0 >= 2048) {
        // V section -> vtout[b][dv][l], dv = col-2048, 4 consecutive l per store
#pragma unroll
        for (int i = 0; i < 4; i++) {
            int row0 = m0 + wm + i * 16 + quad * 4;
            int bb = row0 >> 11, l = row0 & 2047;
#pragma unroll
            for (int j = 0; j < 4; j++) {
                int col = n0 + wn + j * 16 + l16;
                float bv = HASBIAS ? bias[col] : 0.f;
                int dv = col - 2048;
                u32x2 w;
                w.x = pack_bf2(acc[i][j][0] + bv, acc[i][j][1] + bv);
                w.y = pack_bf2(acc[i][j][2] + bv, acc[i][j][3] + bv);
                *(u32x2*)&vtout[((size_t)(bb * 1024 + dv)) * 2048 + l] = w;
            }
        }
        return;
    }

    float* outf = (float*)Cout + (size_t)z * M * N;
    u16* outh = (u16*)Cout + (size_t)z * M * N;
#pragma unroll
    for (int i = 0; i < 4; i++) {
#pragma unroll
        for (int j = 0; j < 4; j++) {
#pragma unroll
            for (int r = 0; r < 4; r++) {
                int row = m0 + wm + i * 16 + quad * 4 + r;
                int col = n0 + wn + j * 16 + l16;
                float v = acc[i][j][r];
                if (HASBIAS) v += bias[col];
                if (RELU) v = v > 0.f ? v : 0.f;
                if (SCALEQ && col < 1024) v *= Q_SCALE;
                if (OUT_F32)
                    outf[(size_t)row * N + col] = v;
                else
                    outh[(size_t)row * N + col] = f2bfraw(v);
            }
        }
    }
}

// ---------------- flash attention, S^T form, v3 + cvt_pk + MFMA row-sum -----
// grid (SEQ/128, NH, BATCH); 8 waves x 512 threads; wave owns 16 q rows.
//  - P never touches LDS: PV's k-axis permuted per 32-slice (pi bijective),
//    V stored pre-permuted so PV B-frag = lane-local packed exp() output.
//  - K double-buffered via global_load_lds with pre-swizzled source.
//  - softmax pack via v_cvt_pk_bf16_f32 (1 VALU vs pack_bf2's 3).
//  - r13: softmax denominator via one extra MFMA per ks with all-ones A
//    (D[m][q] = sum_k P[k][q], rows identical) -> kills 32 v_add/tile + the
//    final cross-quad shuffles; denominator now sums the SAME bf16-rounded P
//    as the numerator (more consistent).
//  - LDS = 2*16384 (K dbuf) + 16384 (V) = 49152 B; 16 waves/CU.
__global__ __launch_bounds__(512, 4) void attn_kernel(const u16* __restrict__ qkv,
                                                      const u16* __restrict__ vt,
                                                      u16* __restrict__ O) {
    __shared__ __attribute__((aligned(16))) u16 Ks[2][128 * 64]; // [k=128][dk=64], swz
    __shared__ __attribute__((aligned(16))) u16 Vs[64 * 128];    // [dv=64][k-permuted], swz

    const int tid = threadIdx.x;
    const int lane = tid & 63, wid = tid >> 6;
    const int quad = lane >> 4, l16 = lane & 15;
    const int sw = l16 & 7;  // row-swizzle key for all l16-row reads
    const int b = blockIdx.z, h = blockIdx.y;
    const int q0 = blockIdx.x * 128 + wid * 16;

    // Q fragments (B-operand: n=q=l16, k=quad*8+j); Q pre-scaled by Q_SCALE
    const size_t qrow = (size_t)(b * SEQ + q0 + l16) * NQKV + h * DK;
    const bf16x8 qf0 = *(const bf16x8*)&qkv[qrow + quad * 8];
    const bf16x8 qf1 = *(const bf16x8*)&qkv[qrow + 32 + quad * 8];

    const u16* Kbase = qkv + (size_t)(b * SEQ) * NQKV + D_MODEL + h * DK;
    const u16* Vbase = vt + (size_t)((b * NH + h) * DK) * SEQ;

    f32x4 oacc[4];
#pragma unroll
    for (int d = 0; d < 4; d++) oacc[d] = (f32x4){0.f, 0.f, 0.f, 0.f};
    const f32x4 Z = {0.f, 0.f, 0.f, 0.f};
    f32x4 sumacc = Z;  // row-sum accumulator (all 4 rows identical)
    const u32 ONE2 = 0x3F803F80u;  // two bf16 1.0
    const u32x4 onesw = (u32x4){ONE2, ONE2, ONE2, ONE2};
    const bf16x8 vones = __builtin_bit_cast(bf16x8, onesw);

    // K tile stage: direct-to-LDS, source pre-swizzled (chunk ^ row&7)
    auto stage_k = [&](int kt2, int buf) {
#pragma unroll
        for (int p = 0; p < 2; p++) {
            int seg = p * 8 + wid;                   // 16 segments of 8 rows
            int row = seg * 8 + (lane >> 3);
            int chunk = (lane & 7) ^ (lane >> 3);    // row&7 == lane>>3
            gload_lds16(&Kbase[(size_t)(kt2 + row) * NQKV + chunk * 8],
                        &Ks[buf][seg * 512]);
        }
    };
    // V tile load to regs (reg-staged: permuted LDS write can't use gload_lds)
    bf16x8 vreg[2];
    auto load_v = [&](int kt2) {
#pragma unroll
        for (int p = 0; p < 2; p++) {
            int s = p * 512 + tid;
            vreg[p] = *(const bf16x8*)&Vbase[(size_t)(s >> 4) * SEQ + kt2 + (s & 15) * 8];
        }
    };
    stage_k(0, 0);
    load_v(0);

    for (int t = 0; t < SEQ / 128; t++) {
        const int kt = t * 128;
        // ---- write V(t) regs -> Vs, k-permuted + swizzled -------------------
#pragma unroll
        for (int p = 0; p < 2; p++) {
            int s = p * 512 + tid;
            int vr = s >> 4, vc = s & 15;
            int chunkA = (vc >> 2) * 4 + (vc & 1) * 2;
            int rem = ((vc >> 1) & 1) * 4;
            u32x4 kv = __builtin_bit_cast(u32x4, vreg[p]);
            *(u32x2*)&Vs[vr * 128 + ((chunkA ^ (vr & 7)) * 8) + rem] =
                (u32x2){kv.x, kv.y};
            *(u32x2*)&Vs[vr * 128 + (((chunkA + 1) ^ (vr & 7)) * 8) + rem] =
                (u32x2){kv.z, kv.w};
        }
        __syncthreads();  // K(t) landed (vmcnt drained), Vs visible to all waves

        // issue next tile's K-to-LDS + V-to-regs; drained at barrier2
        if (t + 1 < SEQ / 128) {
            stage_k(kt + 128, (t + 1) & 1);
            load_v(kt + 128);
        }

        const u16* kb = Ks[t & 1];

        // ---- S^T = K·Q^T : sacc[nt], k=nt*16+quad*4+r, q=l16 ----
        f32x4 sacc[8];
        __builtin_amdgcn_s_setprio(1);
#pragma unroll
        for (int nt = 0; nt < 8; nt++) {
            const u16* krow = &kb[(nt * 16 + l16) * 64];
            bf16x8 kf0 = *(const bf16x8*)&krow[(quad ^ sw) * 8];
            bf16x8 kf1 = *(const bf16x8*)&krow[((4 + quad) ^ sw) * 8];
            f32x4 s0 = __builtin_amdgcn_mfma_f32_16x16x32_bf16(kf0, qf0, Z, 0, 0, 0);
            sacc[nt] = __builtin_amdgcn_mfma_f32_16x16x32_bf16(kf1, qf1, s0, 0, 0, 0);
        }
        __builtin_amdgcn_s_setprio(0);

        // ---- softmax fully in-register: exp2, cvt_pk bf16 (sum via MFMA) ----
        u32 wreg[8][2];
#pragma unroll
        for (int nt = 0; nt < 8; nt++) {
            float p0 = __builtin_amdgcn_exp2f(sacc[nt][0]);
            float p1 = __builtin_amdgcn_exp2f(sacc[nt][1]);
            float p2 = __builtin_amdgcn_exp2f(sacc[nt][2]);
            float p3 = __builtin_amdgcn_exp2f(sacc[nt][3]);
            wreg[nt][0] = cvtpk_bf2(p0, p1);
            wreg[nt][1] = cvtpk_bf2(p2, p3);
        }

        // ---- O^T += V^T·P^T over permuted k: B-frag is lane-local ----
        __builtin_amdgcn_s_setprio(1);
#pragma unroll
        for (int ks = 0; ks < 4; ks++) {
            u32x4 pw = (u32x4){wreg[2 * ks][0], wreg[2 * ks][1],
                               wreg[2 * ks + 1][0], wreg[2 * ks + 1][1]};
            bf16x8 pf = __builtin_bit_cast(bf16x8, pw);
#pragma unroll
            for (int d = 0; d < 4; d++) {
                bf16x8 vf = *(const bf16x8*)&Vs[(d * 16 + l16) * 128 +
                                                (((ks * 4 + quad) ^ sw) * 8)];
                oacc[d] = __builtin_amdgcn_mfma_f32_16x16x32_bf16(vf, pf, oacc[d], 0, 0, 0);
            }
            // denominator: ones-A MFMA sums P over this 32-k slice (free reduce)
            sumacc = __builtin_amdgcn_mfma_f32_16x16x32_bf16(vones, pf, sumacc, 0, 0, 0);
        }
        __builtin_amdgcn_s_setprio(0);
        __syncthreads();  // all waves done with Ks[t&1]/Vs before restage
    }

    // sumacc rows are identical; no cross-lane reduce needed
    float iv = 1.f / sumacc[0];

    // O^T C-layout: col=q=l16, row=dv=d*16+quad*4+r -> b64 stores
    size_t row = (size_t)(b * SEQ + q0 + l16);
#pragma unroll
    for (int d = 0; d < 4; d++) {
        float o0 = oacc[d][0] * iv, o1 = oacc[d][1] * iv;
        float o2 = oacc[d][2] * iv, o3 = oacc[d][3] * iv;
        u32x2 w;
        w.x = ((u32)f2bfraw(o1) << 16) | f2bfraw(o0);
        w.y = ((u32)f2bfraw(o3) << 16) | f2bfraw(o2);
        *(u32x2*)&O[row * D_MODEL + h * DK + d * 16 + quad * 4] = w;
    }
}

// ---------------- LayerNorm(base + sum of P bf16 partial slices) ------------
// Partials layout: slice z at parts + z*BL*D_MODEL (u16 bf16). Summed in f32.
// BASEBF: base stream is bf16 (u16) instead of f32 (saves the f32 h1 stream).
template <int P, int BASEBF>
__global__ __launch_bounds__(256) void lnp_kernel(const void* __restrict__ base,
                                                  const u16* __restrict__ parts,
                                                  const float* __restrict__ g,
                                                  const float* __restrict__ be,
                                                  u16* __restrict__ out_bf,
                                                  float* __restrict__ out_f) {
    int row = blockIdx.x;
    int tid = threadIdx.x;
    int c = tid * 4;
    size_t off = (size_t)row * D_MODEL + c;
    float v[4];
    if (BASEBF) {
        u32x2 bw = *(const u32x2*)&((const u16*)base)[off];
        v[0] = bfraw2f((u16)(bw.x & 0xffffu));
        v[1] = bfraw2f((u16)(bw.x >> 16));
        v[2] = bfraw2f((u16)(bw.y & 0xffffu));
        v[3] = bfraw2f((u16)(bw.y >> 16));
    } else {
        f32x4 bv = *(const f32x4*)&((const float*)base)[off];
        v[0] = bv[0]; v[1] = bv[1]; v[2] = bv[2]; v[3] = bv[3];
    }
#pragma unroll
    for (int z = 0; z < P; z++) {
        u32x2 pw = *(const u32x2*)&parts[(size_t)z * BL * D_MODEL + off];
        v[0] += bfraw2f((u16)(pw.x & 0xffffu));
        v[1] += bfraw2f((u16)(pw.x >> 16));
        v[2] += bfraw2f((u16)(pw.y & 0xffffu));
        v[3] += bfraw2f((u16)(pw.y >> 16));
    }
    float s = 0.f, ss = 0.f;
#pragma unroll
    for (int i = 0; i < 4; i++) {
        s += v[i];
        ss += v[i] * v[i];
    }
#pragma unroll
    for (int off2 = 32; off2; off2 >>= 1) {
        s += __shfl_down(s, off2, 64);
        ss += __shfl_down(ss, off2, 64);
    }
    __shared__ float red[8];
    int wid = tid >> 6, lane = tid & 63;
    if (lane == 0) { red[wid] = s; red[4 + wid] = ss; }
    __syncthreads();
    if (tid == 0) {
        red[0] = red[0] + red[1] + red[2] + red[3];
        red[4] = red[4] + red[5] + red[6] + red[7];
    }
    __syncthreads();
    float mu = red[0] * (1.f / D_MODEL);
    float var = red[4] * (1.f / D_MODEL) - mu * mu;
    float rs = rsqrtf(var + 1e-5f);
#pragma unroll
    for (int i = 0; i < 4; i++) {
        float o = (v[i] - mu) * rs * g[c + i] + be[c + i];
        if (out_f) out_f[(size_t)row * D_MODEL + c + i] = o;
        if (out_bf) out_bf[(size_t)row * D_MODEL + c + i] = f2bfraw(o);
    }
}

// ---------------- launch ----------------
extern "C" void kernel_launch(void* const* d_in, const int* in_sizes, int n_in,
                              void* d_out, int out_size, void* d_ws, size_t ws_size,
                              hipStream_t stream) {
    const float* x   = (const float*)d_in[0];
    const float* Wq  = (const float*)d_in[1];
    const float* bq  = (const float*)d_in[2];
    const float* Wk  = (const float*)d_in[3];
    const float* bk  = (const float*)d_in[4];
    const float* Wv  = (const float*)d_in[5];
    const float* bv  = (const float*)d_in[6];
    const float* Wo  = (const float*)d_in[7];
    const float* g1  = (const float*)d_in[8];
    const float* be1 = (const float*)d_in[9];
    const float* W1  = (const float*)d_in[10];
    const float* b1  = (const float*)d_in[11];
    const float* W2  = (const float*)d_in[12];
    const float* g2  = (const float*)d_in[13];
    const float* be2 = (const float*)d_in[14];

    char* w = (char*)d_ws;
    auto alloc = [&](size_t bytes) {
        char* p = w;
        w += (bytes + 255) & ~(size_t)255;
        return p;
    };
    // Lifetime-aliased workspace (r13): saves ~72MB of footprint, which cuts
    // the harness's per-iteration ws poison/restore traffic.
    u16* wqkv_t = (u16*)alloc((size_t)NQKV * D_MODEL * 2);
    u16* wo_t   = (u16*)alloc((size_t)D_MODEL * D_MODEL * 2);
    u16* w1_t   = (u16*)alloc((size_t)DFF * D_MODEL * 2);
    u16* w2_t   = (u16*)alloc((size_t)D_MODEL * DFF * 2);
    float* bqkv = (float*)alloc((size_t)NQKV * 4);
    u16* x_bf   = (u16*)alloc((size_t)BL * D_MODEL * 2);     // dead after QKV gemm
    u16* qkvbuf = (u16*)alloc((size_t)BL * NQKV * 2);        // dead after attn
    u16* vtbuf  = (u16*)alloc((size_t)BATCH * NH * DK * SEQ * 2);  // dead after attn
    u16* mha_pb = (u16*)alloc((size_t)4 * BL * D_MODEL * 2); // dead after ln1
    u16* h1_bf  = (u16*)alloc((size_t)BL * D_MODEL * 2);     // live to ln2
    u16* obuf   = x_bf;     // attn output: x_bf dead by then (8MB = 8MB)
    u16* ffa    = qkvbuf;   // ffa: qkvbuf+vtbuf dead after attn (24+8 = 32MB)
    u16* ffb_pb = mha_pb;   // ffb partials: mha_pb dead after ln1 (32MB = 32MB)

    // merged prep: all weight transposes + bias concat + x cast (1 launch)
    prep_weights<<<dim3(1024, 1, 7), 256, 0, stream>>>(
        Wq, Wk, Wv, Wo, W1, W2, bq, bk, bv, x,
        wqkv_t, wo_t, w1_t, w2_t, bqkv, x_bf);

    // QKV = x @ Wqkv^T + bias -> Q,K bf16 into qkvbuf; V transposed into vtbuf
    gemm_bt<0, 0, 1, 1, 1, 1><<<dim3(32, 24), 256, 0, stream>>>(
        x_bf, wqkv_t, bqkv, qkvbuf, vtbuf, BL, NQKV, D_MODEL);
    // flash attention -> O bf16 [4096][1024] (obuf aliases x_bf)
    attn_kernel<<<dim3(16, 16, 2), 512, 0, stream>>>(qkvbuf, vtbuf, obuf);
    // mha partials = O @ Wo (split-K=4, bf16 partials) -> 4 blocks/CU
    gemm_bt<0, 0, 0, 4, 0, 0><<<dim3(32, 8, 4), 256, 0, stream>>>(
        obuf, wo_t, nullptr, mha_pb, nullptr, BL, D_MODEL, D_MODEL);
    // h1 = LN(x + sum of 4 mha partials) -> bf16 only
    lnp_kernel<4, 0><<<dim3(BL), 256, 0, stream>>>(x, mha_pb, g1, be1,
                                                   h1_bf, nullptr);
    // ffa = relu(h1 @ W1 + b1) -> bf16 [4096][4096] (aliases qkvbuf+vtbuf)
    gemm_bt<0, 1, 1, 1, 0, 0><<<dim3(32, 32), 256, 0, stream>>>(
        h1_bf, w1_t, b1, ffa, nullptr, BL, DFF, D_MODEL);
    // ffb partials = ffa @ W2 (split-K=4, bf16 partials; aliases mha_pb)
    gemm_bt<0, 0, 0, 4, 0, 0><<<dim3(32, 8, 4), 256, 0, stream>>>(
        ffa, w2_t, nullptr, ffb_pb, nullptr, BL, D_MODEL, DFF);
    // out = LN(h1_bf + sum of 4 ffb partials)
    lnp_kernel<4, 1><<<dim3(BL), 256, 0, stream>>>(h1_bf, ffb_pb, g2, be2,
                                                   nullptr, (float*)d_out);
}

// Round 14
// 330.066 us; speedup vs baseline: 1.1121x; 1.0133x over previous
//
#include <hip/hip_runtime.h>

typedef unsigned short u16;
typedef unsigned int u32;
typedef short bf16x8 __attribute__((ext_vector_type(8)));
typedef float f32x4 __attribute__((ext_vector_type(4)));
typedef unsigned int u32x2 __attribute__((ext_vector_type(2)));
typedef unsigned int u32x4 __attribute__((ext_vector_type(4)));

#define D_MODEL 1024
#define NH 16
#define DK 64
#define DFF 4096
#define BATCH 2
#define SEQ 2048
#define BL (BATCH*SEQ)
#define NQKV 3072
// fold (1/sqrt(64)) * log2(e) into Q so softmax is raw exp2 (v_exp_f32)
#define Q_SCALE 0.18033688011f

__device__ __forceinline__ float bfraw2f(u16 u) {
    union { u32 i; float f; } c; c.i = ((u32)u) << 16; return c.f;
}
__device__ __forceinline__ u16 f2bfraw(float f) {
    union { float f; u32 i; } c; c.f = f;
    u32 i = c.i;
    u32 lsb = (i >> 16) & 1u;
    i += 0x7fffu + lsb;
    return (u16)(i >> 16);
}
__device__ __forceinline__ u32 fasu(float f) {
    union { float f; u32 i; } c; c.f = f; return c.i;
}
// single-instruction pack: dst.lo=bf16(lo), dst.hi=bf16(hi) (RNE). No builtin
// on gfx950 (T12/m240) -> inline asm. 1 VALU vs 3 for the manual pack.
__device__ __forceinline__ u32 cvtpk_bf2(float lo, float hi) {
    u32 r;
    asm("v_cvt_pk_bf16_f32 %0, %1, %2" : "=v"(r) : "v"(lo), "v"(hi));
    return r;
}
// async global->LDS 16B per lane (dest = wave-uniform base + lane*16)
__device__ __forceinline__ void gload_lds16(const u16* g, u16* l) {
    __builtin_amdgcn_global_load_lds(
        (const __attribute__((address_space(1))) void*)g,
        (__attribute__((address_space(3))) void*)l, 16, 0, 0);
}

// ---------------- merged prep: weight transposes + bias concat + x cast -----
// grid (1024, 1, 7), 256 thr.
// z=0..2: Wq/Wk/Wv per-head transpose into fused [3072][1024] B^T layout
//         (z=0 blocks 256..267 also do the bias concat).
// z=3: Wo (1024x1024). z=4: W1 (1024x4096). z=5: W2 (4096x1024).
// z=6: x f32 -> bf16 cast, 4 chunks per block.
__global__ __launch_bounds__(256) void prep_weights(
    const float* __restrict__ Wq, const float* __restrict__ Wk,
    const float* __restrict__ Wv, const float* __restrict__ Wo,
    const float* __restrict__ W1, const float* __restrict__ W2,
    const float* __restrict__ bq, const float* __restrict__ bk,
    const float* __restrict__ bv, const float* __restrict__ x,
    u16* __restrict__ wqkv_t, u16* __restrict__ wo_t,
    u16* __restrict__ w1_t, u16* __restrict__ w2_t,
    float* __restrict__ bqkv, u16* __restrict__ x_bf) {
    __shared__ u16 t[64][65];
    const int z = blockIdx.z, bx = blockIdx.x;
    const int col = threadIdx.x & 63, rr = threadIdx.x >> 6;

    if (z == 6) {
        // cast x: 4096*1024 f32 -> bf16; 1024 blocks x 4 chunks x 1024 elems
#pragma unroll
        for (int j = 0; j < 4; j++) {
            int i = (((j << 10) + bx) * 256 + threadIdx.x) * 4;
            f32x4 v = *(const f32x4*)&x[i];
#pragma unroll
            for (int e = 0; e < 4; e++) x_bf[i + e] = f2bfraw(v[e]);
        }
        return;
    }

    if (z < 3) {
        if (bx >= 256) {
            if (z == 0 && bx < 268) {
                int i = (bx - 256) * 256 + threadIdx.x;
                bqkv[i] = (i < 1024) ? bq[i]
                        : (i < 2048) ? bk[i - 1024] : bv[i - 2048];
            }
            return;
        }
        const int d0 = (bx & 15) * 64, h = bx >> 4;
        const float* W = (z == 0) ? Wq : (z == 1) ? Wk : Wv;
        const float* src = W + (size_t)h * D_MODEL * DK;
        for (int i = rr; i < 64; i += 4)
            t[i][col] = f2bfraw(src[(size_t)(d0 + i) * DK + col]);
        __syncthreads();
        u16* dst = wqkv_t + (size_t)(z * 1024 + h * 64) * D_MODEL;
        for (int i = rr; i < 64; i += 4)
            dst[(size_t)i * D_MODEL + d0 + col] = t[col][i];
        return;
    }

    const float* in; u16* out; int R, C;
    if (z == 3)      { in = Wo; out = wo_t; R = 1024; C = 1024; }
    else if (z == 4) { in = W1; out = w1_t; R = 1024; C = 4096; }
    else             { in = W2; out = w2_t; R = 4096; C = 1024; }
    const int ctiles = C >> 6;
    const int rt = bx / ctiles, ct = bx % ctiles;
    if (rt >= (R >> 6)) return;
    const int c0 = ct * 64, r0 = rt * 64;
    for (int i = rr; i < 64; i += 4)
        t[i][col] = f2bfraw(in[(size_t)(r0 + i) * C + c0 + col]);
    __syncthreads();
    for (int i = rr; i < 64; i += 4)
        out[(size_t)(c0 + i) * R + r0 + col] = t[col][i];
}

// ---------------- GEMM: C[M][N] = A[M][K] @ Bt[N][K]^T ----------------
// m97 structure (r2-exact, session-best): 128x128 tile, BK=64, unpadded LDS,
// global_load_lds width 16, NO XCD swizzle (r7: wrecks A-panel L2 reuse).
// bf16 output path carries the split-K z-offset -> split-K partials can be
// bf16 (halves partial traffic; enables split-K=4 at neutral bytes).
// VSTORE: blocks with n0>=2048 (V section of QKV) store transposed into vtout
//         [b][h][dv][l] as 8B packed bf16.

template <int OUT_F32, int RELU, int HASBIAS, int SPLITK, int SCALEQ, int VSTORE>
__global__ __launch_bounds__(256, 4) void gemm_bt(const u16* __restrict__ A,
                                                  const u16* __restrict__ Bt,
                                                  const float* __restrict__ bias,
                                                  void* __restrict__ Cout,
                                                  u16* __restrict__ vtout,
                                                  int M, int N, int K) {
    __shared__ __attribute__((aligned(16))) u16 As[128 * 64];
    __shared__ __attribute__((aligned(16))) u16 Bs[128 * 64];
    const int tid = threadIdx.x;
    const int lane = tid & 63, wid = tid >> 6;
    const int quad = lane >> 4, l16 = lane & 15;
    const int m0 = blockIdx.x * 128, n0 = blockIdx.y * 128;
    const int z = (SPLITK > 1) ? blockIdx.z : 0;
    const int Klen = K / SPLITK;
    const int kend = (z + 1) * Klen;
    const int wm = (wid >> 1) * 64, wn = (wid & 1) * 64;

    f32x4 acc[4][4];
#pragma unroll
    for (int i = 0; i < 4; i++)
#pragma unroll
        for (int j = 0; j < 4; j++) acc[i][j] = (f32x4){0.f, 0.f, 0.f, 0.f};

    const int srow = lane >> 3, scol = (lane & 7) * 8;

    for (int kb = z * Klen; kb < kend; kb += 64) {
#pragma unroll
        for (int p = 0; p < 4; p++) {
            int c = wid * 4 + p;
            int row = c * 8 + srow;
            gload_lds16(&A[(size_t)(m0 + row) * K + kb + scol], &As[c * 512]);
            gload_lds16(&Bt[(size_t)(n0 + row) * K + kb + scol], &Bs[c * 512]);
        }
        __syncthreads();
#pragma unroll
        for (int kh = 0; kh < 2; kh++) {
            bf16x8 af[4], bf[4];
#pragma unroll
            for (int t = 0; t < 4; t++) {
                af[t] = *(const bf16x8*)&As[(wm + t * 16 + l16) * 64 + kh * 32 + quad * 8];
                bf[t] = *(const bf16x8*)&Bs[(wn + t * 16 + l16) * 64 + kh * 32 + quad * 8];
            }
#pragma unroll
            for (int i = 0; i < 4; i++)
#pragma unroll
                for (int j = 0; j < 4; j++)
                    acc[i][j] = __builtin_amdgcn_mfma_f32_16x16x32_bf16(
                        af[i], bf[j], acc[i][j], 0, 0, 0);
        }
        __syncthreads();
    }

    if (VSTORE && n0 >= 2048) {
        // V section -> vtout[b][dv][l], dv = col-2048, 4 consecutive l per store
#pragma unroll
        for (int i = 0; i < 4; i++) {
            int row0 = m0 + wm + i * 16 + quad * 4;
            int bb = row0 >> 11, l = row0 & 2047;
#pragma unroll
            for (int j = 0; j < 4; j++) {
                int col = n0 + wn + j * 16 + l16;
                float bv = HASBIAS ? bias[col] : 0.f;
                int dv = col - 2048;
                u32x2 w;
                w.x = cvtpk_bf2(acc[i][j][0] + bv, acc[i][j][1] + bv);
                w.y = cvtpk_bf2(acc[i][j][2] + bv, acc[i][j][3] + bv);
                *(u32x2*)&vtout[((size_t)(bb * 1024 + dv)) * 2048 + l] = w;
            }
        }
        return;
    }

    float* outf = (float*)Cout + (size_t)z * M * N;
    u16* outh = (u16*)Cout + (size_t)z * M * N;
#pragma unroll
    for (int i = 0; i < 4; i++) {
#pragma unroll
        for (int j = 0; j < 4; j++) {
#pragma unroll
            for (int r = 0; r < 4; r++) {
                int row = m0 + wm + i * 16 + quad * 4 + r;
                int col = n0 + wn + j * 16 + l16;
                float v = acc[i][j][r];
                if (HASBIAS) v += bias[col];
                if (RELU) v = v > 0.f ? v : 0.f;
                if (SCALEQ && col < 1024) v *= Q_SCALE;
                if (OUT_F32)
                    outf[(size_t)row * N + col] = v;
                else
                    outh[(size_t)row * N + col] = f2bfraw(v);
            }
        }
    }
}

// ---------------- flash attention, S^T form, v3 + cvt_pk + MFMA row-sum -----
// grid (SEQ/128, NH, BATCH); 8 waves x 512 threads; wave owns 16 q rows.
//  - P never touches LDS: PV's k-axis permuted per 32-slice (pi bijective),
//    V stored pre-permuted so PV B-frag = lane-local packed exp() output.
//  - K double-buffered via global_load_lds with pre-swizzled source.
//  - softmax pack via v_cvt_pk_bf16_f32 (1 VALU vs 3).
//  - softmax denominator via ones-A MFMA (free reduce on matrix pipe; no
//    cross-lane shuffles; denominator sums the SAME bf16-rounded P as PV).
//  - LDS = 2*16384 (K dbuf) + 16384 (V) = 49152 B; 16 waves/CU.
__global__ __launch_bounds__(512, 4) void attn_kernel(const u16* __restrict__ qkv,
                                                      const u16* __restrict__ vt,
                                                      u16* __restrict__ O) {
    __shared__ __attribute__((aligned(16))) u16 Ks[2][128 * 64]; // [k=128][dk=64], swz
    __shared__ __attribute__((aligned(16))) u16 Vs[64 * 128];    // [dv=64][k-permuted], swz

    const int tid = threadIdx.x;
    const int lane = tid & 63, wid = tid >> 6;
    const int quad = lane >> 4, l16 = lane & 15;
    const int sw = l16 & 7;  // row-swizzle key for all l16-row reads
    const int b = blockIdx.z, h = blockIdx.y;
    const int q0 = blockIdx.x * 128 + wid * 16;

    // Q fragments (B-operand: n=q=l16, k=quad*8+j); Q pre-scaled by Q_SCALE
    const size_t qrow = (size_t)(b * SEQ + q0 + l16) * NQKV + h * DK;
    const bf16x8 qf0 = *(const bf16x8*)&qkv[qrow + quad * 8];
    const bf16x8 qf1 = *(const bf16x8*)&qkv[qrow + 32 + quad * 8];

    const u16* Kbase = qkv + (size_t)(b * SEQ) * NQKV + D_MODEL + h * DK;
    const u16* Vbase = vt + (size_t)((b * NH + h) * DK) * SEQ;

    f32x4 oacc[4];
#pragma unroll
    for (int d = 0; d < 4; d++) oacc[d] = (f32x4){0.f, 0.f, 0.f, 0.f};
    const f32x4 Z = {0.f, 0.f, 0.f, 0.f};
    f32x4 sumacc = Z;  // row-sum accumulator (all 4 rows identical)
    const u32 ONE2 = 0x3F803F80u;  // two bf16 1.0
    const u32x4 onesw = (u32x4){ONE2, ONE2, ONE2, ONE2};
    const bf16x8 vones = __builtin_bit_cast(bf16x8, onesw);

    // K tile stage: direct-to-LDS, source pre-swizzled (chunk ^ row&7)
    auto stage_k = [&](int kt2, int buf) {
#pragma unroll
        for (int p = 0; p < 2; p++) {
            int seg = p * 8 + wid;                   // 16 segments of 8 rows
            int row = seg * 8 + (lane >> 3);
            int chunk = (lane & 7) ^ (lane >> 3);    // row&7 == lane>>3
            gload_lds16(&Kbase[(size_t)(kt2 + row) * NQKV + chunk * 8],
                        &Ks[buf][seg * 512]);
        }
    };
    // V tile load to regs (reg-staged: permuted LDS write can't use gload_lds)
    bf16x8 vreg[2];
    auto load_v = [&](int kt2) {
#pragma unroll
        for (int p = 0; p < 2; p++) {
            int s = p * 512 + tid;
            vreg[p] = *(const bf16x8*)&Vbase[(size_t)(s >> 4) * SEQ + kt2 + (s & 15) * 8];
        }
    };
    stage_k(0, 0);
    load_v(0);

    for (int t = 0; t < SEQ / 128; t++) {
        const int kt = t * 128;
        // ---- write V(t) regs -> Vs, k-permuted + swizzled -------------------
#pragma unroll
        for (int p = 0; p < 2; p++) {
            int s = p * 512 + tid;
            int vr = s >> 4, vc = s & 15;
            int chunkA = (vc >> 2) * 4 + (vc & 1) * 2;
            int rem = ((vc >> 1) & 1) * 4;
            u32x4 kv = __builtin_bit_cast(u32x4, vreg[p]);
            *(u32x2*)&Vs[vr * 128 + ((chunkA ^ (vr & 7)) * 8) + rem] =
                (u32x2){kv.x, kv.y};
            *(u32x2*)&Vs[vr * 128 + (((chunkA + 1) ^ (vr & 7)) * 8) + rem] =
                (u32x2){kv.z, kv.w};
        }
        __syncthreads();  // K(t) landed (vmcnt drained), Vs visible to all waves

        // issue next tile's K-to-LDS + V-to-regs; drained at barrier2
        if (t + 1 < SEQ / 128) {
            stage_k(kt + 128, (t + 1) & 1);
            load_v(kt + 128);
        }

        const u16* kb = Ks[t & 1];

        // ---- S^T = K·Q^T : sacc[nt], k=nt*16+quad*4+r, q=l16 ----
        f32x4 sacc[8];
        __builtin_amdgcn_s_setprio(1);
#pragma unroll
        for (int nt = 0; nt < 8; nt++) {
            const u16* krow = &kb[(nt * 16 + l16) * 64];
            bf16x8 kf0 = *(const bf16x8*)&krow[(quad ^ sw) * 8];
            bf16x8 kf1 = *(const bf16x8*)&krow[((4 + quad) ^ sw) * 8];
            f32x4 s0 = __builtin_amdgcn_mfma_f32_16x16x32_bf16(kf0, qf0, Z, 0, 0, 0);
            sacc[nt] = __builtin_amdgcn_mfma_f32_16x16x32_bf16(kf1, qf1, s0, 0, 0, 0);
        }
        __builtin_amdgcn_s_setprio(0);

        // ---- softmax fully in-register: exp2, cvt_pk bf16 (sum via MFMA) ----
        u32 wreg[8][2];
#pragma unroll
        for (int nt = 0; nt < 8; nt++) {
            float p0 = __builtin_amdgcn_exp2f(sacc[nt][0]);
            float p1 = __builtin_amdgcn_exp2f(sacc[nt][1]);
            float p2 = __builtin_amdgcn_exp2f(sacc[nt][2]);
            float p3 = __builtin_amdgcn_exp2f(sacc[nt][3]);
            wreg[nt][0] = cvtpk_bf2(p0, p1);
            wreg[nt][1] = cvtpk_bf2(p2, p3);
        }

        // ---- O^T += V^T·P^T over permuted k: B-frag is lane-local ----
        __builtin_amdgcn_s_setprio(1);
#pragma unroll
        for (int ks = 0; ks < 4; ks++) {
            u32x4 pw = (u32x4){wreg[2 * ks][0], wreg[2 * ks][1],
                               wreg[2 * ks + 1][0], wreg[2 * ks + 1][1]};
            bf16x8 pf = __builtin_bit_cast(bf16x8, pw);
#pragma unroll
            for (int d = 0; d < 4; d++) {
                bf16x8 vf = *(const bf16x8*)&Vs[(d * 16 + l16) * 128 +
                                                (((ks * 4 + quad) ^ sw) * 8)];
                oacc[d] = __builtin_amdgcn_mfma_f32_16x16x32_bf16(vf, pf, oacc[d], 0, 0, 0);
            }
            // denominator: ones-A MFMA sums P over this 32-k slice (free reduce)
            sumacc = __builtin_amdgcn_mfma_f32_16x16x32_bf16(vones, pf, sumacc, 0, 0, 0);
        }
        __builtin_amdgcn_s_setprio(0);
        __syncthreads();  // all waves done with Ks[t&1]/Vs before restage
    }

    // sumacc rows are identical; no cross-lane reduce needed
    float iv = 1.f / sumacc[0];

    // O^T C-layout: col=q=l16, row=dv=d*16+quad*4+r -> b64 stores
    size_t row = (size_t)(b * SEQ + q0 + l16);
#pragma unroll
    for (int d = 0; d < 4; d++) {
        u32x2 w;
        w.x = cvtpk_bf2(oacc[d][0] * iv, oacc[d][1] * iv);
        w.y = cvtpk_bf2(oacc[d][2] * iv, oacc[d][3] * iv);
        *(u32x2*)&O[row * D_MODEL + h * DK + d * 16 + quad * 4] = w;
    }
}

// ---------------- LayerNorm(base + sum of P bf16 partial slices) ------------
// Partials layout: slice z at parts + z*BL*D_MODEL (u16 bf16). Summed in f32.
// BASEBF: base stream is bf16 (u16) instead of f32 (saves the f32 h1 stream).
template <int P, int BASEBF>
__global__ __launch_bounds__(256) void lnp_kernel(const void* __restrict__ base,
                                                  const u16* __restrict__ parts,
                                                  const float* __restrict__ g,
                                                  const float* __restrict__ be,
                                                  u16* __restrict__ out_bf,
                                                  float* __restrict__ out_f) {
    int row = blockIdx.x;
    int tid = threadIdx.x;
    int c = tid * 4;
    size_t off = (size_t)row * D_MODEL + c;
    float v[4];
    if (BASEBF) {
        u32x2 bw = *(const u32x2*)&((const u16*)base)[off];
        v[0] = bfraw2f((u16)(bw.x & 0xffffu));
        v[1] = bfraw2f((u16)(bw.x >> 16));
        v[2] = bfraw2f((u16)(bw.y & 0xffffu));
        v[3] = bfraw2f((u16)(bw.y >> 16));
    } else {
        f32x4 bv = *(const f32x4*)&((const float*)base)[off];
        v[0] = bv[0]; v[1] = bv[1]; v[2] = bv[2]; v[3] = bv[3];
    }
#pragma unroll
    for (int z = 0; z < P; z++) {
        u32x2 pw = *(const u32x2*)&parts[(size_t)z * BL * D_MODEL + off];
        v[0] += bfraw2f((u16)(pw.x & 0xffffu));
        v[1] += bfraw2f((u16)(pw.x >> 16));
        v[2] += bfraw2f((u16)(pw.y & 0xffffu));
        v[3] += bfraw2f((u16)(pw.y >> 16));
    }
    float s = 0.f, ss = 0.f;
#pragma unroll
    for (int i = 0; i < 4; i++) {
        s += v[i];
        ss += v[i] * v[i];
    }
#pragma unroll
    for (int off2 = 32; off2; off2 >>= 1) {
        s += __shfl_down(s, off2, 64);
        ss += __shfl_down(ss, off2, 64);
    }
    __shared__ float red[8];
    int wid = tid >> 6, lane = tid & 63;
    if (lane == 0) { red[wid] = s; red[4 + wid] = ss; }
    __syncthreads();
    if (tid == 0) {
        red[0] = red[0] + red[1] + red[2] + red[3];
        red[4] = red[4] + red[5] + red[6] + red[7];
    }
    __syncthreads();
    float mu = red[0] * (1.f / D_MODEL);
    float var = red[4] * (1.f / D_MODEL) - mu * mu;
    float rs = rsqrtf(var + 1e-5f);
    float o[4];
#pragma unroll
    for (int i = 0; i < 4; i++)
        o[i] = (v[i] - mu) * rs * g[c + i] + be[c + i];
    if (out_f) {
#pragma unroll
        for (int i = 0; i < 4; i++)
            out_f[(size_t)row * D_MODEL + c + i] = o[i];
    }
    if (out_bf) {
        u32x2 w;
        w.x = cvtpk_bf2(o[0], o[1]);
        w.y = cvtpk_bf2(o[2], o[3]);
        *(u32x2*)&out_bf[(size_t)row * D_MODEL + c] = w;
    }
}

// ---------------- launch ----------------
extern "C" void kernel_launch(void* const* d_in, const int* in_sizes, int n_in,
                              void* d_out, int out_size, void* d_ws, size_t ws_size,
                              hipStream_t stream) {
    const float* x   = (const float*)d_in[0];
    const float* Wq  = (const float*)d_in[1];
    const float* bq  = (const float*)d_in[2];
    const float* Wk  = (const float*)d_in[3];
    const float* bk  = (const float*)d_in[4];
    const float* Wv  = (const float*)d_in[5];
    const float* bv  = (const float*)d_in[6];
    const float* Wo  = (const float*)d_in[7];
    const float* g1  = (const float*)d_in[8];
    const float* be1 = (const float*)d_in[9];
    const float* W1  = (const float*)d_in[10];
    const float* b1  = (const float*)d_in[11];
    const float* W2  = (const float*)d_in[12];
    const float* g2  = (const float*)d_in[13];
    const float* be2 = (const float*)d_in[14];

    char* w = (char*)d_ws;
    auto alloc = [&](size_t bytes) {
        char* p = w;
        w += (bytes + 255) & ~(size_t)255;
        return p;
    };
    // Lifetime-aliased workspace (r14): 72MB footprint (was 104MB). Region R
    // (32MB) serializes three strictly-sequential tenants:
    //   qkvbuf+vtbuf [written d1, read d2] -> mha_pb [d3, d4] -> ffa [d5, d6].
    // ffb_pb gets its own 32MB [d6, d7]; obuf aliases x_bf [d2, d3].
    u16* wqkv_t = (u16*)alloc((size_t)NQKV * D_MODEL * 2);
    u16* wo_t   = (u16*)alloc((size_t)D_MODEL * D_MODEL * 2);
    u16* w1_t   = (u16*)alloc((size_t)DFF * D_MODEL * 2);
    u16* w2_t   = (u16*)alloc((size_t)D_MODEL * DFF * 2);
    float* bqkv = (float*)alloc((size_t)NQKV * 4);
    u16* x_bf   = (u16*)alloc((size_t)BL * D_MODEL * 2);       // then obuf
    u16* regR   = (u16*)alloc((size_t)BL * NQKV * 2 + (size_t)BATCH * NH * DK * SEQ * 2);
    u16* ffb_pb = (u16*)alloc((size_t)4 * BL * D_MODEL * 2);
    u16* h1_bf  = (u16*)alloc((size_t)BL * D_MODEL * 2);

    u16* qkvbuf = regR;                                   // [d1, d2]
    u16* vtbuf  = regR + (size_t)BL * NQKV;                // [d1, d2]
    u16* mha_pb = regR;                                    // [d3, d4]
    u16* ffa    = regR;                                    // [d5, d6]
    u16* obuf   = x_bf;                                    // [d2, d3]

    // d0: merged prep (all weight transposes + bias concat + x cast)
    prep_weights<<<dim3(1024, 1, 7), 256, 0, stream>>>(
        Wq, Wk, Wv, Wo, W1, W2, bq, bk, bv, x,
        wqkv_t, wo_t, w1_t, w2_t, bqkv, x_bf);

    // d1: QKV = x @ Wqkv^T + bias -> Q,K bf16 into qkvbuf; V^T into vtbuf
    gemm_bt<0, 0, 1, 1, 1, 1><<<dim3(32, 24), 256, 0, stream>>>(
        x_bf, wqkv_t, bqkv, qkvbuf, vtbuf, BL, NQKV, D_MODEL);
    // d2: flash attention -> O bf16 [4096][1024] (obuf aliases x_bf)
    attn_kernel<<<dim3(16, 16, 2), 512, 0, stream>>>(qkvbuf, vtbuf, obuf);
    // d3: mha partials = O @ Wo (split-K=4, bf16 partials; mha_pb aliases regR)
    gemm_bt<0, 0, 0, 4, 0, 0><<<dim3(32, 8, 4), 256, 0, stream>>>(
        obuf, wo_t, nullptr, mha_pb, nullptr, BL, D_MODEL, D_MODEL);
    // d4: h1 = LN(x + sum of 4 mha partials) -> bf16 only
    lnp_kernel<4, 0><<<dim3(BL), 256, 0, stream>>>(x, mha_pb, g1, be1,
                                                   h1_bf, nullptr);
    // d5: ffa = relu(h1 @ W1 + b1) -> bf16 [4096][4096] (ffa aliases regR)
    gemm_bt<0, 1, 1, 1, 0, 0><<<dim3(32, 32), 256, 0, stream>>>(
        h1_bf, w1_t, b1, ffa, nullptr, BL, DFF, D_MODEL);
    // d6: ffb partials = ffa @ W2 (split-K=4, bf16 partials)
    gemm_bt<0, 0, 0, 4, 0, 0><<<dim3(32, 8, 4), 256, 0, stream>>>(
        ffa, w2_t, nullptr, ffb_pb, nullptr, BL, D_MODEL, DFF);
    // d7: out = LN(h1_bf + sum of 4 ffb partials)
    lnp_kernel<4, 1><<<dim3(BL), 256, 0, stream>>>(h1_bf, ffb_pb, g2, be2,
                                                   nullptr, (float*)d_out);
}

// Round 15
// 326.078 us; speedup vs baseline: 1.1257x; 1.0122x over previous
//
#include <hip/hip_runtime.h>

typedef unsigned short u16;
typedef unsigned int u32;
typedef short bf16x8 __attribute__((ext_vector_type(8)));
typedef float f32x4 __attribute__((ext_vector_type(4)));
typedef unsigned int u32x2 __attribute__((ext_vector_type(2)));
typedef unsigned int u32x4 __attribute__((ext_vector_type(4)));

#define D_MODEL 1024
#define NH 16
#define DK 64
#define DFF 4096
#define BATCH 2
#define SEQ 2048
#define BL (BATCH*SEQ)
#define NQKV 3072
// fold (1/sqrt(64)) * log2(e) into Q so softmax is raw exp2 (v_exp_f32)
#define Q_SCALE 0.18033688011f

__device__ __forceinline__ float bfraw2f(u16 u) {
    union { u32 i; float f; } c; c.i = ((u32)u) << 16; return c.f;
}
__device__ __forceinline__ u16 f2bfraw(float f) {
    union { float f; u32 i; } c; c.f = f;
    u32 i = c.i;
    u32 lsb = (i >> 16) & 1u;
    i += 0x7fffu + lsb;
    return (u16)(i >> 16);
}
__device__ __forceinline__ u32 fasu(float f) {
    union { float f; u32 i; } c; c.f = f; return c.i;
}
// single-instruction pack: dst.lo=bf16(lo), dst.hi=bf16(hi) (RNE). No builtin
// on gfx950 (T12/m240) -> inline asm. 1 VALU vs 3 for the manual pack.
__device__ __forceinline__ u32 cvtpk_bf2(float lo, float hi) {
    u32 r;
    asm("v_cvt_pk_bf16_f32 %0, %1, %2" : "=v"(r) : "v"(lo), "v"(hi));
    return r;
}
// async global->LDS 16B per lane (dest = wave-uniform base + lane*16)
__device__ __forceinline__ void gload_lds16(const u16* g, u16* l) {
    __builtin_amdgcn_global_load_lds(
        (const __attribute__((address_space(1))) void*)g,
        (__attribute__((address_space(3))) void*)l, 16, 0, 0);
}

// ---------------- merged prep: weight transposes + bias concat + x cast -----
// grid (1024, 1, 7), 256 thr.
// z=0..2: Wq/Wk/Wv per-head transpose into fused [3072][1024] B^T layout
//         (z=0 blocks 256..267 also do the bias concat).
// z=3: Wo (1024x1024). z=4: W1 (1024x4096). z=5: W2 (4096x1024).
// z=6: x f32 -> bf16 cast, 4 chunks per block.
__global__ __launch_bounds__(256) void prep_weights(
    const float* __restrict__ Wq, const float* __restrict__ Wk,
    const float* __restrict__ Wv, const float* __restrict__ Wo,
    const float* __restrict__ W1, const float* __restrict__ W2,
    const float* __restrict__ bq, const float* __restrict__ bk,
    const float* __restrict__ bv, const float* __restrict__ x,
    u16* __restrict__ wqkv_t, u16* __restrict__ wo_t,
    u16* __restrict__ w1_t, u16* __restrict__ w2_t,
    float* __restrict__ bqkv, u16* __restrict__ x_bf) {
    __shared__ u16 t[64][65];
    const int z = blockIdx.z, bx = blockIdx.x;
    const int col = threadIdx.x & 63, rr = threadIdx.x >> 6;

    if (z == 6) {
        // cast x: 4096*1024 f32 -> bf16; 1024 blocks x 4 chunks x 1024 elems
#pragma unroll
        for (int j = 0; j < 4; j++) {
            int i = (((j << 10) + bx) * 256 + threadIdx.x) * 4;
            f32x4 v = *(const f32x4*)&x[i];
#pragma unroll
            for (int e = 0; e < 4; e++) x_bf[i + e] = f2bfraw(v[e]);
        }
        return;
    }

    if (z < 3) {
        if (bx >= 256) {
            if (z == 0 && bx < 268) {
                int i = (bx - 256) * 256 + threadIdx.x;
                bqkv[i] = (i < 1024) ? bq[i]
                        : (i < 2048) ? bk[i - 1024] : bv[i - 2048];
            }
            return;
        }
        const int d0 = (bx & 15) * 64, h = bx >> 4;
        const float* W = (z == 0) ? Wq : (z == 1) ? Wk : Wv;
        const float* src = W + (size_t)h * D_MODEL * DK;
        for (int i = rr; i < 64; i += 4)
            t[i][col] = f2bfraw(src[(size_t)(d0 + i) * DK + col]);
        __syncthreads();
        u16* dst = wqkv_t + (size_t)(z * 1024 + h * 64) * D_MODEL;
        for (int i = rr; i < 64; i += 4)
            dst[(size_t)i * D_MODEL + d0 + col] = t[col][i];
        return;
    }

    const float* in; u16* out; int R, C;
    if (z == 3)      { in = Wo; out = wo_t; R = 1024; C = 1024; }
    else if (z == 4) { in = W1; out = w1_t; R = 1024; C = 4096; }
    else             { in = W2; out = w2_t; R = 4096; C = 1024; }
    const int ctiles = C >> 6;
    const int rt = bx / ctiles, ct = bx % ctiles;
    if (rt >= (R >> 6)) return;
    const int c0 = ct * 64, r0 = rt * 64;
    for (int i = rr; i < 64; i += 4)
        t[i][col] = f2bfraw(in[(size_t)(r0 + i) * C + c0 + col]);
    __syncthreads();
    for (int i = rr; i < 64; i += 4)
        out[(size_t)(c0 + i) * R + r0 + col] = t[col][i];
}

// ---------------- GEMM: C[M][N] = A[M][K] @ Bt[N][K]^T ----------------
// m97 structure (r2-exact, session-best): 128x128 tile, BK=64, unpadded LDS,
// global_load_lds width 16, NO XCD swizzle (r7: wrecks A-panel L2 reuse).
// bf16 split-K partials (halves partial traffic; enables split-K=4).
// SPLITOUT: bf16 partial slices go to two bases: z<2 -> Cout, z>=2 -> vtout
//           (lets partials reuse dead 16MB regions; vtout is free then).
// VSTORE: blocks with n0>=2048 (V section of QKV) store transposed into vtout
//         [b][h][dv][l] as 8B packed bf16.

template <int OUT_F32, int RELU, int HASBIAS, int SPLITK, int SCALEQ, int VSTORE,
          int SPLITOUT>
__global__ __launch_bounds__(256, 4) void gemm_bt(const u16* __restrict__ A,
                                                  const u16* __restrict__ Bt,
                                                  const float* __restrict__ bias,
                                                  void* __restrict__ Cout,
                                                  u16* __restrict__ vtout,
                                                  int M, int N, int K) {
    __shared__ __attribute__((aligned(16))) u16 As[128 * 64];
    __shared__ __attribute__((aligned(16))) u16 Bs[128 * 64];
    const int tid = threadIdx.x;
    const int lane = tid & 63, wid = tid >> 6;
    const int quad = lane >> 4, l16 = lane & 15;
    const int m0 = blockIdx.x * 128, n0 = blockIdx.y * 128;
    const int z = (SPLITK > 1) ? blockIdx.z : 0;
    const int Klen = K / SPLITK;
    const int kend = (z + 1) * Klen;
    const int wm = (wid >> 1) * 64, wn = (wid & 1) * 64;

    f32x4 acc[4][4];
#pragma unroll
    for (int i = 0; i < 4; i++)
#pragma unroll
        for (int j = 0; j < 4; j++) acc[i][j] = (f32x4){0.f, 0.f, 0.f, 0.f};

    const int srow = lane >> 3, scol = (lane & 7) * 8;

    for (int kb = z * Klen; kb < kend; kb += 64) {
#pragma unroll
        for (int p = 0; p < 4; p++) {
            int c = wid * 4 + p;
            int row = c * 8 + srow;
            gload_lds16(&A[(size_t)(m0 + row) * K + kb + scol], &As[c * 512]);
            gload_lds16(&Bt[(size_t)(n0 + row) * K + kb + scol], &Bs[c * 512]);
        }
        __syncthreads();
#pragma unroll
        for (int kh = 0; kh < 2; kh++) {
            bf16x8 af[4], bf[4];
#pragma unroll
            for (int t = 0; t < 4; t++) {
                af[t] = *(const bf16x8*)&As[(wm + t * 16 + l16) * 64 + kh * 32 + quad * 8];
                bf[t] = *(const bf16x8*)&Bs[(wn + t * 16 + l16) * 64 + kh * 32 + quad * 8];
            }
#pragma unroll
            for (int i = 0; i < 4; i++)
#pragma unroll
                for (int j = 0; j < 4; j++)
                    acc[i][j] = __builtin_amdgcn_mfma_f32_16x16x32_bf16(
                        af[i], bf[j], acc[i][j], 0, 0, 0);
        }
        __syncthreads();
    }

    if (VSTORE && n0 >= 2048) {
        // V section -> vtout[b][dv][l], dv = col-2048, 4 consecutive l per store
#pragma unroll
        for (int i = 0; i < 4; i++) {
            int row0 = m0 + wm + i * 16 + quad * 4;
            int bb = row0 >> 11, l = row0 & 2047;
#pragma unroll
            for (int j = 0; j < 4; j++) {
                int col = n0 + wn + j * 16 + l16;
                float bv = HASBIAS ? bias[col] : 0.f;
                int dv = col - 2048;
                u32x2 w;
                w.x = cvtpk_bf2(acc[i][j][0] + bv, acc[i][j][1] + bv);
                w.y = cvtpk_bf2(acc[i][j][2] + bv, acc[i][j][3] + bv);
                *(u32x2*)&vtout[((size_t)(bb * 1024 + dv)) * 2048 + l] = w;
            }
        }
        return;
    }

    float* outf = (float*)Cout + (size_t)z * M * N;
    u16* outh;
    if (SPLITOUT) {
        u16* base = (z < 2) ? (u16*)Cout : vtout;
        outh = base + (size_t)(z & 1) * M * N;
    } else {
        outh = (u16*)Cout + (size_t)z * M * N;
    }
#pragma unroll
    for (int i = 0; i < 4; i++) {
#pragma unroll
        for (int j = 0; j < 4; j++) {
#pragma unroll
            for (int r = 0; r < 4; r++) {
                int row = m0 + wm + i * 16 + quad * 4 + r;
                int col = n0 + wn + j * 16 + l16;
                float v = acc[i][j][r];
                if (HASBIAS) v += bias[col];
                if (RELU) v = v > 0.f ? v : 0.f;
                if (SCALEQ && col < 1024) v *= Q_SCALE;
                if (OUT_F32)
                    outf[(size_t)row * N + col] = v;
                else
                    outh[(size_t)row * N + col] = f2bfraw(v);
            }
        }
    }
}

// ---------------- flash attention, S^T form, v3 + cvt_pk + MFMA row-sum -----
// grid (512); 8 waves x 512 threads; wave owns 16 q rows.
//  - r15: XCD-grouped flat grid: d = (g&7) + 8*j + 128*(g>>3), g=(b,h) group,
//    j=q-tile. All 16 q-tiles of a group satisfy d==g (mod 8) -> same XCD
//    under round-robin -> K/V (512KB/group) fetched once per XCD L2
//    (4 groups x 512KB fits 4MB). Bijective; pure permutation (T1, correct
//    direction: colocate sharers — r7's failure separated them).
//  - P never touches LDS: PV's k-axis permuted per 32-slice (pi bijective),
//    V stored pre-permuted so PV B-frag = lane-local packed exp() output.
//  - K double-buffered via global_load_lds with pre-swizzled source.
//  - softmax pack via v_cvt_pk_bf16_f32; denominator via ones-A MFMA.
//  - LDS = 2*16384 (K dbuf) + 16384 (V) = 49152 B; 16 waves/CU.
__global__ __launch_bounds__(512, 4) void attn_kernel(const u16* __restrict__ qkv,
                                                      const u16* __restrict__ vt,
                                                      u16* __restrict__ O) {
    __shared__ __attribute__((aligned(16))) u16 Ks[2][128 * 64]; // [k=128][dk=64], swz
    __shared__ __attribute__((aligned(16))) u16 Vs[64 * 128];    // [dv=64][k-permuted], swz

    const int tid = threadIdx.x;
    const int lane = tid & 63, wid = tid >> 6;
    const int quad = lane >> 4, l16 = lane & 15;
    const int sw = l16 & 7;  // row-swizzle key for all l16-row reads
    const int dd = blockIdx.x;
    const int g = (dd & 7) + ((dd >> 7) << 3);   // (b,h) group 0..31
    const int j = (dd >> 3) & 15;                // q-tile 0..15
    const int h = g & 15, b = g >> 4;
    const int q0 = j * 128 + wid * 16;

    // Q fragments (B-operand: n=q=l16, k=quad*8+j); Q pre-scaled by Q_SCALE
    const size_t qrow = (size_t)(b * SEQ + q0 + l16) * NQKV + h * DK;
    const bf16x8 qf0 = *(const bf16x8*)&qkv[qrow + quad * 8];
    const bf16x8 qf1 = *(const bf16x8*)&qkv[qrow + 32 + quad * 8];

    const u16* Kbase = qkv + (size_t)(b * SEQ) * NQKV + D_MODEL + h * DK;
    const u16* Vbase = vt + (size_t)((b * NH + h) * DK) * SEQ;

    f32x4 oacc[4];
#pragma unroll
    for (int d = 0; d < 4; d++) oacc[d] = (f32x4){0.f, 0.f, 0.f, 0.f};
    const f32x4 Z = {0.f, 0.f, 0.f, 0.f};
    f32x4 sumacc = Z;  // row-sum accumulator (all 4 rows identical)
    const u32 ONE2 = 0x3F803F80u;  // two bf16 1.0
    const u32x4 onesw = (u32x4){ONE2, ONE2, ONE2, ONE2};
    const bf16x8 vones = __builtin_bit_cast(bf16x8, onesw);

    // K tile stage: direct-to-LDS, source pre-swizzled (chunk ^ row&7)
    auto stage_k = [&](int kt2, int buf) {
#pragma unroll
        for (int p = 0; p < 2; p++) {
            int seg = p * 8 + wid;                   // 16 segments of 8 rows
            int row = seg * 8 + (lane >> 3);
            int chunk = (lane & 7) ^ (lane >> 3);    // row&7 == lane>>3
            gload_lds16(&Kbase[(size_t)(kt2 + row) * NQKV + chunk * 8],
                        &Ks[buf][seg * 512]);
        }
    };
    // V tile load to regs (reg-staged: permuted LDS write can't use gload_lds)
    bf16x8 vreg[2];
    auto load_v = [&](int kt2) {
#pragma unroll
        for (int p = 0; p < 2; p++) {
            int s = p * 512 + tid;
            vreg[p] = *(const bf16x8*)&Vbase[(size_t)(s >> 4) * SEQ + kt2 + (s & 15) * 8];
        }
    };
    stage_k(0, 0);
    load_v(0);

    for (int t = 0; t < SEQ / 128; t++) {
        const int kt = t * 128;
        // ---- write V(t) regs -> Vs, k-permuted + swizzled -------------------
#pragma unroll
        for (int p = 0; p < 2; p++) {
            int s = p * 512 + tid;
            int vr = s >> 4, vc = s & 15;
            int chunkA = (vc >> 2) * 4 + (vc & 1) * 2;
            int rem = ((vc >> 1) & 1) * 4;
            u32x4 kv = __builtin_bit_cast(u32x4, vreg[p]);
            *(u32x2*)&Vs[vr * 128 + ((chunkA ^ (vr & 7)) * 8) + rem] =
                (u32x2){kv.x, kv.y};
            *(u32x2*)&Vs[vr * 128 + (((chunkA + 1) ^ (vr & 7)) * 8) + rem] =
                (u32x2){kv.z, kv.w};
        }
        __syncthreads();  // K(t) landed (vmcnt drained), Vs visible to all waves

        // issue next tile's K-to-LDS + V-to-regs; drained at barrier2
        if (t + 1 < SEQ / 128) {
            stage_k(kt + 128, (t + 1) & 1);
            load_v(kt + 128);
        }

        const u16* kb = Ks[t & 1];

        // ---- S^T = K·Q^T : sacc[nt], k=nt*16+quad*4+r, q=l16 ----
        f32x4 sacc[8];
        __builtin_amdgcn_s_setprio(1);
#pragma unroll
        for (int nt = 0; nt < 8; nt++) {
            const u16* krow = &kb[(nt * 16 + l16) * 64];
            bf16x8 kf0 = *(const bf16x8*)&krow[(quad ^ sw) * 8];
            bf16x8 kf1 = *(const bf16x8*)&krow[((4 + quad) ^ sw) * 8];
            f32x4 s0 = __builtin_amdgcn_mfma_f32_16x16x32_bf16(kf0, qf0, Z, 0, 0, 0);
            sacc[nt] = __builtin_amdgcn_mfma_f32_16x16x32_bf16(kf1, qf1, s0, 0, 0, 0);
        }
        __builtin_amdgcn_s_setprio(0);

        // ---- softmax fully in-register: exp2, cvt_pk bf16 (sum via MFMA) ----
        u32 wreg[8][2];
#pragma unroll
        for (int nt = 0; nt < 8; nt++) {
            float p0 = __builtin_amdgcn_exp2f(sacc[nt][0]);
            float p1 = __builtin_amdgcn_exp2f(sacc[nt][1]);
            float p2 = __builtin_amdgcn_exp2f(sacc[nt][2]);
            float p3 = __builtin_amdgcn_exp2f(sacc[nt][3]);
            wreg[nt][0] = cvtpk_bf2(p0, p1);
            wreg[nt][1] = cvtpk_bf2(p2, p3);
        }

        // ---- O^T += V^T·P^T over permuted k: B-frag is lane-local ----
        __builtin_amdgcn_s_setprio(1);
#pragma unroll
        for (int ks = 0; ks < 4; ks++) {
            u32x4 pw = (u32x4){wreg[2 * ks][0], wreg[2 * ks][1],
                               wreg[2 * ks + 1][0], wreg[2 * ks + 1][1]};
            bf16x8 pf = __builtin_bit_cast(bf16x8, pw);
#pragma unroll
            for (int d = 0; d < 4; d++) {
                bf16x8 vf = *(const bf16x8*)&Vs[(d * 16 + l16) * 128 +
                                                (((ks * 4 + quad) ^ sw) * 8)];
                oacc[d] = __builtin_amdgcn_mfma_f32_16x16x32_bf16(vf, pf, oacc[d], 0, 0, 0);
            }
            // denominator: ones-A MFMA sums P over this 32-k slice (free reduce)
            sumacc = __builtin_amdgcn_mfma_f32_16x16x32_bf16(vones, pf, sumacc, 0, 0, 0);
        }
        __builtin_amdgcn_s_setprio(0);
        __syncthreads();  // all waves done with Ks[t&1]/Vs before restage
    }

    // sumacc rows are identical; no cross-lane reduce needed
    float iv = 1.f / sumacc[0];

    // O^T C-layout: col=q=l16, row=dv=d*16+quad*4+r -> b64 stores
    size_t row = (size_t)(b * SEQ + q0 + l16);
#pragma unroll
    for (int d = 0; d < 4; d++) {
        u32x2 w;
        w.x = cvtpk_bf2(oacc[d][0] * iv, oacc[d][1] * iv);
        w.y = cvtpk_bf2(oacc[d][2] * iv, oacc[d][3] * iv);
        *(u32x2*)&O[row * D_MODEL + h * DK + d * 16 + quad * 4] = w;
    }
}

// ---------------- LayerNorm(base + sum of PA+PB bf16 partial slices) --------
// partsA holds PA slices (stride BL*D_MODEL), partsB holds PB more. f32 sum.
// BASEBF: base stream is bf16 (u16) instead of f32.
template <int PA, int PB, int BASEBF>
__global__ __launch_bounds__(256) void lnp_kernel(const void* __restrict__ base,
                                                  const u16* __restrict__ partsA,
                                                  const u16* __restrict__ partsB,
                                                  const float* __restrict__ g,
                                                  const float* __restrict__ be,
                                                  u16* __restrict__ out_bf,
                                                  float* __restrict__ out_f) {
    int row = blockIdx.x;
    int tid = threadIdx.x;
    int c = tid * 4;
    size_t off = (size_t)row * D_MODEL + c;
    float v[4];
    if (BASEBF) {
        u32x2 bw = *(const u32x2*)&((const u16*)base)[off];
        v[0] = bfraw2f((u16)(bw.x & 0xffffu));
        v[1] = bfraw2f((u16)(bw.x >> 16));
        v[2] = bfraw2f((u16)(bw.y & 0xffffu));
        v[3] = bfraw2f((u16)(bw.y >> 16));
    } else {
        f32x4 bv = *(const f32x4*)&((const float*)base)[off];
        v[0] = bv[0]; v[1] = bv[1]; v[2] = bv[2]; v[3] = bv[3];
    }
#pragma unroll
    for (int z = 0; z < PA; z++) {
        u32x2 pw = *(const u32x2*)&partsA[(size_t)z * BL * D_MODEL + off];
        v[0] += bfraw2f((u16)(pw.x & 0xffffu));
        v[1] += bfraw2f((u16)(pw.x >> 16));
        v[2] += bfraw2f((u16)(pw.y & 0xffffu));
        v[3] += bfraw2f((u16)(pw.y >> 16));
    }
#pragma unroll
    for (int z = 0; z < PB; z++) {
        u32x2 pw = *(const u32x2*)&partsB[(size_t)z * BL * D_MODEL + off];
        v[0] += bfraw2f((u16)(pw.x & 0xffffu));
        v[1] += bfraw2f((u16)(pw.x >> 16));
        v[2] += bfraw2f((u16)(pw.y & 0xffffu));
        v[3] += bfraw2f((u16)(pw.y >> 16));
    }
    float s = 0.f, ss = 0.f;
#pragma unroll
    for (int i = 0; i < 4; i++) {
        s += v[i];
        ss += v[i] * v[i];
    }
#pragma unroll
    for (int off2 = 32; off2; off2 >>= 1) {
        s += __shfl_down(s, off2, 64);
        ss += __shfl_down(ss, off2, 64);
    }
    __shared__ float red[8];
    int wid = tid >> 6, lane = tid & 63;
    if (lane == 0) { red[wid] = s; red[4 + wid] = ss; }
    __syncthreads();
    if (tid == 0) {
        red[0] = red[0] + red[1] + red[2] + red[3];
        red[4] = red[4] + red[5] + red[6] + red[7];
    }
    __syncthreads();
    float mu = red[0] * (1.f / D_MODEL);
    float var = red[4] * (1.f / D_MODEL) - mu * mu;
    float rs = rsqrtf(var + 1e-5f);
    float o[4];
#pragma unroll
    for (int i = 0; i < 4; i++)
        o[i] = (v[i] - mu) * rs * g[c + i] + be[c + i];
    if (out_f) {
#pragma unroll
        for (int i = 0; i < 4; i++)
            out_f[(size_t)row * D_MODEL + c + i] = o[i];
    }
    if (out_bf) {
        u32x2 w;
        w.x = cvtpk_bf2(o[0], o[1]);
        w.y = cvtpk_bf2(o[2], o[3]);
        *(u32x2*)&out_bf[(size_t)row * D_MODEL + c] = w;
    }
}

// ---------------- launch ----------------
extern "C" void kernel_launch(void* const* d_in, const int* in_sizes, int n_in,
                              void* d_out, int out_size, void* d_ws, size_t ws_size,
                              hipStream_t stream) {
    const float* x   = (const float*)d_in[0];
    const float* Wq  = (const float*)d_in[1];
    const float* bq  = (const float*)d_in[2];
    const float* Wk  = (const float*)d_in[3];
    const float* bk  = (const float*)d_in[4];
    const float* Wv  = (const float*)d_in[5];
    const float* bv  = (const float*)d_in[6];
    const float* Wo  = (const float*)d_in[7];
    const float* g1  = (const float*)d_in[8];
    const float* be1 = (const float*)d_in[9];
    const float* W1  = (const float*)d_in[10];
    const float* b1  = (const float*)d_in[11];
    const float* W2  = (const float*)d_in[12];
    const float* g2  = (const float*)d_in[13];
    const float* be2 = (const float*)d_in[14];

    char* w = (char*)d_ws;
    auto alloc = [&](size_t bytes) {
        char* p = w;
        w += (bytes + 255) & ~(size_t)255;
        return p;
    };
    // Lifetime-aliased workspace (r15): 88MB footprint (was 104MB).
    //   regR (32MB): qkvbuf+vtbuf [d1,d2] -> mha_pb [d3,d4] -> ffa [d5,d6]
    //   obuf = x_bf [d2,d3]
    //   ffb partials z0,z1 -> wqkv_t..w1_t span (16MB, dead after d5) [d6,d7]
    //   ffb partials z2,z3 -> pb23 (16MB) [d6,d7]
    // NOTE: wqkv_t(6MB), wo_t(2MB), w1_t(8MB) are consecutive 256B-aligned
    // allocs with 256-multiple sizes -> contiguous 16MB span from wqkv_t.
    u16* wqkv_t = (u16*)alloc((size_t)NQKV * D_MODEL * 2);
    u16* wo_t   = (u16*)alloc((size_t)D_MODEL * D_MODEL * 2);
    u16* w1_t   = (u16*)alloc((size_t)DFF * D_MODEL * 2);
    u16* w2_t   = (u16*)alloc((size_t)D_MODEL * DFF * 2);
    float* bqkv = (float*)alloc((size_t)NQKV * 4);
    u16* x_bf   = (u16*)alloc((size_t)BL * D_MODEL * 2);       // then obuf
    u16* regR   = (u16*)alloc((size_t)BL * NQKV * 2 + (size_t)BATCH * NH * DK * SEQ * 2);
    u16* pb23   = (u16*)alloc((size_t)2 * BL * D_MODEL * 2);
    u16* h1_bf  = (u16*)alloc((size_t)BL * D_MODEL * 2);

    u16* qkvbuf = regR;                                    // [d1, d2]
    u16* vtbuf  = regR + (size_t)BL * NQKV;                // [d1, d2]
    u16* mha_pb = regR;                                    // [d3, d4]
    u16* ffa    = regR;                                    // [d5, d6]
    u16* obuf   = x_bf;                                    // [d2, d3]
    u16* pb01   = wqkv_t;                                  // [d6, d7]

    // d0: merged prep (all weight transposes + bias concat + x cast)
    prep_weights<<<dim3(1024, 1, 7), 256, 0, stream>>>(
        Wq, Wk, Wv, Wo, W1, W2, bq, bk, bv, x,
        wqkv_t, wo_t, w1_t, w2_t, bqkv, x_bf);

    // d1: QKV = x @ Wqkv^T + bias -> Q,K bf16 into qkvbuf; V^T into vtbuf
    gemm_bt<0, 0, 1, 1, 1, 1, 0><<<dim3(32, 24), 256, 0, stream>>>(
        x_bf, wqkv_t, bqkv, qkvbuf, vtbuf, BL, NQKV, D_MODEL);
    // d2: flash attention -> O bf16 [4096][1024] (obuf aliases x_bf)
    attn_kernel<<<dim3(512), 512, 0, stream>>>(qkvbuf, vtbuf, obuf);
    // d3: mha partials = O @ Wo (split-K=4, bf16 partials; mha_pb aliases regR)
    gemm_bt<0, 0, 0, 4, 0, 0, 0><<<dim3(32, 8, 4), 256, 0, stream>>>(
        obuf, wo_t, nullptr, mha_pb, nullptr, BL, D_MODEL, D_MODEL);
    // d4: h1 = LN(x + sum of 4 mha partials) -> bf16 only
    lnp_kernel<4, 0, 0><<<dim3(BL), 256, 0, stream>>>(x, mha_pb, nullptr,
                                                      g1, be1, h1_bf, nullptr);
    // d5: ffa = relu(h1 @ W1 + b1) -> bf16 [4096][4096] (ffa aliases regR)
    gemm_bt<0, 1, 1, 1, 0, 0, 0><<<dim3(32, 32), 256, 0, stream>>>(
        h1_bf, w1_t, b1, ffa, nullptr, BL, DFF, D_MODEL);
    // d6: ffb partials = ffa @ W2 (split-K=4, bf16; z0,z1->pb01, z2,z3->pb23)
    gemm_bt<0, 0, 0, 4, 0, 0, 1><<<dim3(32, 8, 4), 256, 0, stream>>>(
        ffa, w2_t, nullptr, pb01, pb23, BL, D_MODEL, DFF);
    // d7: out = LN(h1_bf + sum of 4 ffb partials)
    lnp_kernel<2, 2, 1><<<dim3(BL), 256, 0, stream>>>(h1_bf, pb01, pb23,
                                                      g2, be2, nullptr,
                                                      (float*)d_out);
}